// Round 13
// baseline (163.342 us; speedup 1.0000x reference)
//
#include <hip/hip_runtime.h>
#include <hip/hip_fp16.h>

#define EPSF 1e-6f

typedef _Float16 f16x8 __attribute__((ext_vector_type(8)));
typedef float f32x4 __attribute__((ext_vector_type(4)));

#define BK 32                  // K-tile (halves); LDS A row = 64 B (4 x 16B segs)
#define SMEM_BYTES 20480       // 4 x 5120 A staging (2 fg regions x 9472 alias inside)
#define BUF_BYTES 5120         // A staging: 80 rows x 64 B

#define AS1 __attribute__((address_space(1)))
#define AS3 __attribute__((address_space(3)))

#define VM_WAIT(N) asm volatile("s_waitcnt vmcnt(" #N ")" ::: "memory")
#define LGKM0()    asm volatile("s_waitcnt lgkmcnt(0)" ::: "memory")

// ---------- wave sum -> scalar (SGPR), fused-DPP version ----------
__device__ __forceinline__ float wave_sum_fast(float x) {
    asm volatile(
        "s_nop 1\n\t"
        "v_add_f32 %0, %0, %0 quad_perm:[1,0,3,2] row_mask:0xf bank_mask:0xf bound_ctrl:0\n\t"
        "s_nop 1\n\t"
        "v_add_f32 %0, %0, %0 quad_perm:[2,3,0,1] row_mask:0xf bank_mask:0xf bound_ctrl:0\n\t"
        "s_nop 1\n\t"
        "v_add_f32 %0, %0, %0 row_half_mirror row_mask:0xf bank_mask:0xf bound_ctrl:0\n\t"
        "s_nop 1\n\t"
        "v_add_f32 %0, %0, %0 row_mirror row_mask:0xf bank_mask:0xf bound_ctrl:0\n\t"
        "s_nop 1\n\t"
        "v_add_f32 %0, %0, %0 row_bcast:15 row_mask:0xf bank_mask:0xf bound_ctrl:0\n\t"
        "s_nop 1\n\t"
        "v_add_f32 %0, %0, %0 row_bcast:31 row_mask:0xf bank_mask:0xf bound_ctrl:0"
        : "+v"(x));
    return __int_as_float(__builtin_amdgcn_readlane(__float_as_int(x), 63));
}

// ---------------- Phase 1: prepend cls, +EPS, L2-normalize, store fp16 ----------------
// A: row-major [64 groups][80 rows][1024]; rows 0..36 = img 2g, 37..73 = img 2g+1.
// B: FRAGMENT-MAJOR by K-32 subtile: Bh[((t*32 + k32)*4 + n)*512 + lane*8].
__global__ __launch_bounds__(256) void norm_kernel(
        const float* __restrict__ img_cls, const float* __restrict__ imgs,
        const float* __restrict__ cap_cls, const float* __restrict__ caps,
        __half* __restrict__ Ah, __half* __restrict__ Bh) {
    __shared__ float red[4];
    const int row = blockIdx.x;
    const int tid = threadIdx.x;

    const float* src = nullptr;
    __half* dsth;
    float eps_add = EPSF;
    if (row < 64 * 80) {
        const int g = row / 80, r = row % 80;
        dsth = Ah + (size_t)row * 1024 + tid * 4;
        int i = -1, rr = 0;
        if (r < 37)      { i = 2 * g;     rr = r; }
        else if (r < 74) { i = 2 * g + 1; rr = r - 37; }
        if (i >= 0) {
            if (rr == 0) { src = img_cls + (size_t)i * 1024; eps_add = 0.0f; }
            else         { src = imgs + ((size_t)i * 36 + (rr - 1)) * 1024; }
        }
    } else {
        const int row2 = row - 64 * 80;
        const int t = row2 >> 6, r = row2 & 63;
        const int n = r >> 4, fr = r & 15;
        const int kt = tid >> 3, q4 = (tid >> 1) & 3, j = (tid & 1) * 4;
        dsth = Bh + ((size_t)(t * 32 + kt) * 4 + n) * 512 + (q4 * 16 + fr) * 8 + j;
        if (r == 0)       { src = cap_cls + (size_t)t * 1024; eps_add = 0.0f; }
        else if (r <= 50) { src = caps + ((size_t)t * 50 + (r - 1)) * 1024; }
    }

    if (src == nullptr) {  // pad row: zeros (uniform across block)
        ushort4 z; z.x = z.y = z.z = z.w = 0;
        *reinterpret_cast<ushort4*>(dsth) = z;
        return;
    }

    float4 v = reinterpret_cast<const float4*>(src)[tid];
    v.x += eps_add; v.y += eps_add; v.z += eps_add; v.w += eps_add;
    float ss = v.x * v.x + v.y * v.y + v.z * v.z + v.w * v.w;
    #pragma unroll
    for (int m = 1; m <= 32; m <<= 1) ss += __shfl_xor(ss, m);
    if ((tid & 63) == 0) red[tid >> 6] = ss;
    __syncthreads();
    const float tot = red[0] + red[1] + red[2] + red[3];
    const float rn = 1.0f / sqrtf(tot);

    ushort4 o;
    o.x = __half_as_ushort(__float2half(v.x * rn));
    o.y = __half_as_ushort(__float2half(v.y * rn));
    o.z = __half_as_ushort(__float2half(v.z * rn));
    o.w = __half_as_ushort(__float2half(v.w * rn));
    *reinterpret_cast<ushort4*>(dsth) = o;
}

// ---------------- Phase 2: fused GEMM + Sinkhorn, 2-wave / 80x64 blocks ----------------
// Block tile 80 A rows (1 img pair) x 64 B cols (1 cap), 128 threads.
// Wave w covers cols w*32..w*32+31 (B frags w*2, w*2+1); each wave computes
// 80x32 -> acc 5x2 = 40 AGPR.  8 blocks/CU (LDS 20,480 x 8 = 160 KiB) =
// 8 independent barrier/vmcnt domains per CU at 16 waves/CU.
// A in LDS: 4 buffers, staged 3 tiles ahead; conflict-free XOR swizzle.
// B direct global->VGPR (fragment-major), double-buffered 2 tiles ahead.
// One barrier per tile.  5 A-hexadecets/tile: wave 0 takes o=0,2,4 (a=3),
// wave 1 takes o=1,3 (a=2).  Steady vmcnt leaves
// [A(kt+2)a, B(kt+2)2, A(kt+3)a] = 2a+2 -> 8 / 6.
__device__ __forceinline__ void stage_octA(const __half* __restrict__ Ag,
                                           __half* buf, int kb, int o, size_t lofs) {
    const __half* src = Ag + (size_t)o * 16384 + kb + lofs;   // 16 rows x 1024 halves
    __builtin_amdgcn_global_load_lds((const AS1 void*)src,
                                     (AS3 void*)(buf + o * 512), 16, 0, 0);
}

__device__ __forceinline__ void stage_A(const __half* __restrict__ Ag,
                                        __half* buf, int kb, int wave, size_t lofs) {
    stage_octA(Ag, buf, kb, wave, lofs);          // o = 0 / 1
    stage_octA(Ag, buf, kb, wave + 2, lofs);      // o = 2 / 3
    if (wave == 0) stage_octA(Ag, buf, kb, 4, lofs);
}

__device__ __forceinline__ void ds_af(const __half* buf, int fr, int q4,
                                      f16x8 af[5]) {
    const int soff = ((q4 ^ ((fr >> 1) & 3)) * 8);   // swizzled seg, halves
    #pragma unroll
    for (int m = 0; m < 5; ++m) {
        const int R = m * 16 + fr;
        af[m] = *reinterpret_cast<const f16x8*>(buf + R * BK + soff);
    }
}

__device__ __forceinline__ void load_bf(const __half* __restrict__ Bgw, int kt,
                                        f16x8 bf[2]) {
    const __half* p = Bgw + (size_t)kt * 2048;   // Bgw has +frag_base+lane*8
    bf[0] = *reinterpret_cast<const f16x8*>(p);
    bf[1] = *reinterpret_cast<const f16x8*>(p + 512);
}

__device__ __forceinline__ void mfma_cluster(f32x4 acc[5][2], const f16x8 af[5],
                                             const f16x8 bf[2]) {
    __builtin_amdgcn_s_setprio(1);
    #pragma unroll
    for (int m = 0; m < 5; ++m)
        #pragma unroll
        for (int n = 0; n < 2; ++n)
            acc[m][n] = __builtin_amdgcn_mfma_f32_16x16x32_f16(af[m], bf[n], acc[m][n], 0, 0, 0);
    __builtin_amdgcn_s_setprio(0);
}

__global__ __launch_bounds__(128, 4) void fused_kernel(
        const __half* __restrict__ Ah, const __half* __restrict__ Bh,
        const int* __restrict__ img_lens, const int* __restrict__ cap_lens,
        float* __restrict__ out) {
    __shared__ __align__(16) char smem[SMEM_BYTES];   // 20,480 B -> 8 blocks/CU
    __half* lds0 = reinterpret_cast<__half*>(smem);
    __half* lds1 = reinterpret_cast<__half*>(smem + BUF_BYTES);
    __half* lds2 = reinterpret_cast<__half*>(smem + 2 * BUF_BYTES);
    __half* lds3 = reinterpret_cast<__half*>(smem + 3 * BUF_BYTES);

    // XCD-chunked mapping: 8 consecutive blocks share bx across 8 by slices.
    const int idx = blockIdx.x;            // 0..8191
    const int xcd = idx & 7;
    const int within = idx >> 3;           // 0..1023
    const int bx = within >> 4;            // 0..63   (A group = img pair)
    const int by = xcd * 16 + (within & 15); // 0..127 (single cap)

    const int tid = threadIdx.x;
    const int wave = tid >> 6;             // 0..1
    const int lane = tid & 63;
    const int fr = lane & 15;
    const int q4 = lane >> 4;

    const __half* Ag = Ah + (size_t)bx * 80 * 1024;
    // wave's frag base = wave*2 of cap by's 4 frags
    const __half* Bgw = Bh + (size_t)by * 65536
                           + (size_t)(wave * 2) * 512 + lane * 8;

    // A staging source: rsub = lane>>2 (row in hexadecet); stored slot (lane&3)
    // holds global seg (lane&3) ^ ((lane>>3)&3).  LDS dest linear.
    const int rsub = lane >> 2;
    const int segsrc = (lane & 3) ^ ((lane >> 3) & 3);
    const size_t lofs = (size_t)rsub * 1024 + (size_t)(segsrc * 8);

    f32x4 acc[5][2];
    #pragma unroll
    for (int m = 0; m < 5; ++m)
        #pragma unroll
        for (int n = 0; n < 2; ++n) {
            f32x4 z = {0.0f, 0.0f, 0.0f, 0.0f};
            acc[m][n] = z;
        }

    f16x8 bfA[2], bfB[2];

    // Prologue.  Queue: [B0·2, A0·a, B1·2, A1·a, A2·a]; wait leaves 2+2a.
    load_bf(Bgw, 0, bfA);
    stage_A(Ag, lds0, 0, wave, lofs);
    load_bf(Bgw, 1, bfB);
    stage_A(Ag, lds1, BK, wave, lofs);
    stage_A(Ag, lds2, 2 * BK, wave, lofs);
    if (wave == 0) { VM_WAIT(8); } else { VM_WAIT(6); }
    __builtin_amdgcn_s_barrier();

    // Tile kt: ds af(buf[kt&3]); MFMA; load B(kt+2); lgkm0 (own reads
    // retired); stage A(kt+3) into the buffer read at kt-1 (its reads
    // retired at kt-1's lgkm0 + barrier); vmcnt(2a+2) [A(kt+1), B(kt+1)
    // landed]; barrier.
    #define GEMM_TILE(KT, RDBUF, STBUF, CUR)                          \
    {                                                                 \
        f16x8 af[5];                                                  \
        ds_af((RDBUF), fr, q4, af);                                   \
        mfma_cluster(acc, af, (CUR));                                 \
        load_bf(Bgw, (KT) + 2, (CUR));                                \
        LGKM0();                                                      \
        stage_A(Ag, (STBUF), ((KT) + 3) * BK, wave, lofs);            \
        if (wave == 0) { VM_WAIT(8); } else { VM_WAIT(6); }           \
        __builtin_amdgcn_s_barrier();                                 \
    }

    #pragma unroll 1
    for (int kt = 0; kt < 28; kt += 4) {
        GEMM_TILE(kt,     lds0, lds3, bfA);
        GEMM_TILE(kt + 1, lds1, lds0, bfB);
        GEMM_TILE(kt + 2, lds2, lds1, bfA);
        GEMM_TILE(kt + 3, lds3, lds2, bfB);
    }
    GEMM_TILE(28, lds0, lds3, bfA);   // stages A31, loads B30
    #undef GEMM_TILE

    // ---- tile 29: no staging; load B31 ----
    {
        f16x8 af[5];
        ds_af(lds1, fr, q4, af);
        mfma_cluster(acc, af, bfB);            // B(29)
        load_bf(Bgw, 31, bfB);
        LGKM0();
        // queue: A30·a, B30·2, A31·a, B31·2 ; need A30,B30 -> leave a+2
        if (wave == 0) { VM_WAIT(5); } else { VM_WAIT(4); }
        __builtin_amdgcn_s_barrier();
    }
    // ---- tile 30 ----
    {
        f16x8 af[5];
        ds_af(lds2, fr, q4, af);
        mfma_cluster(acc, af, bfA);            // B(30)
        LGKM0();
        VM_WAIT(2);                            // A31 landed; B31 in flight
        __builtin_amdgcn_s_barrier();
    }
    // ---- tile 31 ----
    {
        f16x8 af[5];
        ds_af(lds3, fr, q4, af);
        VM_WAIT(0);                            // B31 landed
        mfma_cluster(acc, af, bfB);
    }

    __syncthreads();   // staging buffers become fg scratch (block-shared)

    // ---------------- fg scatter: 2 regions of 37x64 f32 (9,472 B each) ----------------
    // Region rg = s covers (img 2bx+s, cap by).  Wave w writes rows 0..73
    // x its 32 cols (sc = w*32 + n*16 + fr).
    // Cols XOR-swizzled: col ^ (((sr>>2)&3)<<4) -> Sinkhorn reads conflict-free.
    float* fgall = reinterpret_cast<float*>(smem);
    {
        #pragma unroll
        for (int m = 0; m < 5; ++m) {
            #pragma unroll
            for (int q = 0; q < 4; ++q) {
                const int Rl = m * 16 + q4 * 4 + q;     // 0..79
                const int s = (Rl >= 37) ? 1 : 0;
                const int sr = Rl - 37 * s;             // scratch row
                const bool valid = (Rl < 74);
                const int sw = ((sr >> 2) & 3) << 4;
                #pragma unroll
                for (int n = 0; n < 2; ++n) {
                    const int sc = wave * 32 + n * 16 + fr;
                    if (valid)
                        fgall[s * 2368 + sr * 64 + (sc ^ sw)] = acc[m][n][q];
                }
            }
        }
    }
    __syncthreads();   // both regions complete

    // ---------------- Sinkhorn: one task per wave, chunk-skipped + fused DPP ----------------
    // Wave w handles region w: img i = 2bx + w, cap t = by.
    {
        float* fg = fgall + wave * 2368;
        const int i = 2 * bx + wave;
        const int t = by;
        const int il = img_lens[i] + 1;        // 2..37
        const int cl = cap_lens[t] + 1;        // 2..51
        const bool vcol = lane < cl;

        #define FGR(r_) fg[(r_) * 64 + (lane ^ ((((r_) >> 2) & 3) << 4))]
        #define CEND(c_) ((((c_) * 8 + 8) < 37) ? ((c_) * 8 + 8) : 37)

        float P[37];
        #pragma unroll
        for (int r = 0; r < 37; ++r) P[r] = 0.0f;

        float ts[4] = {0.f, 0.f, 0.f, 0.f};
        #pragma unroll
        for (int c = 0; c < 5; ++c) {
            if (c * 8 < il) {                       // wave-uniform chunk skip
                #pragma unroll
                for (int r = c * 8; r < CEND(c); ++r) {
                    const float f = FGR(r);
                    const bool act = (r < il) && vcol;
                    const float pe = act ? __expf((f - 1.0f) * 10.0f) : 0.0f;
                    P[r] = pe;
                    ts[r & 3] += pe;
                }
            }
        }
        float tot = (ts[0] + ts[1]) + (ts[2] + ts[3]);
        tot = wave_sum_fast(tot);
        const float s0 = __builtin_amdgcn_rcpf(tot + EPSF);
        #pragma unroll
        for (int c = 0; c < 5; ++c) {
            if (c * 8 < il) {
                #pragma unroll
                for (int r = c * 8; r < CEND(c); ++r) P[r] *= s0;
            }
        }

        const float rmarg = 1.0f / (float)il;
        const float cmarg = 1.0f / (float)cl;
        float csave = 0.0f;
        for (int it = 0; it < 3; ++it) {
            #pragma unroll
            for (int c = 0; c < 5; ++c) {
                if (c * 8 < il) {
                    #pragma unroll
                    for (int r = c * 8; r < CEND(c); ++r) {   // 8 indep chains
                        const float u = wave_sum_fast(P[r]);
                        P[r] *= rmarg * __builtin_amdgcn_rcpf(u + EPSF);
                    }
                }
            }
            float vs[4] = {EPSF, 0.f, 0.f, 0.f};
            #pragma unroll
            for (int c = 0; c < 5; ++c) {
                if (c * 8 < il) {
                    #pragma unroll
                    for (int r = c * 8; r < CEND(c); ++r) vs[r & 3] += P[r];
                }
            }
            const float v = (vs[0] + vs[1]) + (vs[2] + vs[3]);
            const float cs = vcol ? cmarg * __builtin_amdgcn_rcpf(v) : 0.0f;
            if (it < 2) {
                #pragma unroll
                for (int c = 0; c < 5; ++c) {
                    if (c * 8 < il) {
                        #pragma unroll
                        for (int r = c * 8; r < CEND(c); ++r) P[r] *= cs;
                    }
                }
            } else {
                csave = cs;                               // fold last scale into dot
            }
        }

        float ls[4] = {0.f, 0.f, 0.f, 0.f};
        #pragma unroll
        for (int c = 0; c < 5; ++c) {
            if (c * 8 < il) {
                #pragma unroll
                for (int r = c * 8; r < CEND(c); ++r) {
                    const float f = FGR(r);
                    const float fm = (r < il) ? f : 0.0f;   // mask BEFORE multiply
                    ls[r & 3] = fmaf(fm, P[r], ls[r & 3]);
                }
            }
        }
        float local = csave * ((ls[0] + ls[1]) + (ls[2] + ls[3]));
        local = wave_sum_fast(local);
        if (lane == 0) out[i * 128 + t] = local;
        #undef FGR
        #undef CEND
    }
}

extern "C" void kernel_launch(void* const* d_in, const int* in_sizes, int n_in,
                              void* d_out, int out_size, void* d_ws, size_t ws_size,
                              hipStream_t stream) {
    const float* img_cls  = (const float*)d_in[0];
    const float* imgs     = (const float*)d_in[1];
    const float* cap_cls  = (const float*)d_in[2];
    const float* caps     = (const float*)d_in[3];
    const int*   img_lens = (const int*)d_in[4];
    const int*   cap_lens = (const int*)d_in[5];
    float* out = (float*)d_out;

    __half* Ah = (__half*)d_ws;                          // 64*80*1024 halves = 10.5 MB
    __half* Bh = Ah + (size_t)64 * 80 * 1024;            // 128*64*1024 halves = 16.8 MB

    norm_kernel<<<64 * 80 + 128 * 64, 256, 0, stream>>>(img_cls, imgs, cap_cls, caps, Ah, Bh);
    fused_kernel<<<8192, 128, 0, stream>>>(Ah, Bh, img_lens, cap_lens, out);
}

// Round 14
// 147.024 us; speedup vs baseline: 1.1110x; 1.1110x over previous
//
#include <hip/hip_runtime.h>
#include <hip/hip_fp16.h>

#define EPSF 1e-6f

typedef _Float16 f16x8 __attribute__((ext_vector_type(8)));
typedef float f32x4 __attribute__((ext_vector_type(4)));

#define BK 64                  // K-tile (halves); LDS A row = 128 B (8 x 16B segs)
#define SMEM_BYTES 37888       // 4 fg regions x 37x64 f32 (3 x 10240 A staging aliases front)
#define BUF_BYTES 10240        // A staging: 80 rows x 128 B

#define AS1 __attribute__((address_space(1)))
#define AS3 __attribute__((address_space(3)))

#define VM_WAIT(N) asm volatile("s_waitcnt vmcnt(" #N ")" ::: "memory")
#define LGKM0()    asm volatile("s_waitcnt lgkmcnt(0)" ::: "memory")

// ---------- wave sum -> scalar (SGPR), fused-DPP version ----------
__device__ __forceinline__ float wave_sum_fast(float x) {
    asm volatile(
        "s_nop 1\n\t"
        "v_add_f32 %0, %0, %0 quad_perm:[1,0,3,2] row_mask:0xf bank_mask:0xf bound_ctrl:0\n\t"
        "s_nop 1\n\t"
        "v_add_f32 %0, %0, %0 quad_perm:[2,3,0,1] row_mask:0xf bank_mask:0xf bound_ctrl:0\n\t"
        "s_nop 1\n\t"
        "v_add_f32 %0, %0, %0 row_half_mirror row_mask:0xf bank_mask:0xf bound_ctrl:0\n\t"
        "s_nop 1\n\t"
        "v_add_f32 %0, %0, %0 row_mirror row_mask:0xf bank_mask:0xf bound_ctrl:0\n\t"
        "s_nop 1\n\t"
        "v_add_f32 %0, %0, %0 row_bcast:15 row_mask:0xf bank_mask:0xf bound_ctrl:0\n\t"
        "s_nop 1\n\t"
        "v_add_f32 %0, %0, %0 row_bcast:31 row_mask:0xf bank_mask:0xf bound_ctrl:0"
        : "+v"(x));
    return __int_as_float(__builtin_amdgcn_readlane(__float_as_int(x), 63));
}

// ---------------- Phase 1: prepend cls, +EPS, L2-normalize, store fp16 ----------------
// A: row-major [64 groups][80 rows][1024]; rows 0..36 = img 2g, 37..73 = img 2g+1.
// B: FRAGMENT-MAJOR by K-32 subtile: Bh[((t*32 + k32)*4 + n)*512 + lane*8].
__global__ __launch_bounds__(256) void norm_kernel(
        const float* __restrict__ img_cls, const float* __restrict__ imgs,
        const float* __restrict__ cap_cls, const float* __restrict__ caps,
        __half* __restrict__ Ah, __half* __restrict__ Bh) {
    __shared__ float red[4];
    const int row = blockIdx.x;
    const int tid = threadIdx.x;

    const float* src = nullptr;
    __half* dsth;
    float eps_add = EPSF;
    if (row < 64 * 80) {
        const int g = row / 80, r = row % 80;
        dsth = Ah + (size_t)row * 1024 + tid * 4;
        int i = -1, rr = 0;
        if (r < 37)      { i = 2 * g;     rr = r; }
        else if (r < 74) { i = 2 * g + 1; rr = r - 37; }
        if (i >= 0) {
            if (rr == 0) { src = img_cls + (size_t)i * 1024; eps_add = 0.0f; }
            else         { src = imgs + ((size_t)i * 36 + (rr - 1)) * 1024; }
        }
    } else {
        const int row2 = row - 64 * 80;
        const int t = row2 >> 6, r = row2 & 63;
        const int n = r >> 4, fr = r & 15;
        const int kt = tid >> 3, q4 = (tid >> 1) & 3, j = (tid & 1) * 4;
        dsth = Bh + ((size_t)(t * 32 + kt) * 4 + n) * 512 + (q4 * 16 + fr) * 8 + j;
        if (r == 0)       { src = cap_cls + (size_t)t * 1024; eps_add = 0.0f; }
        else if (r <= 50) { src = caps + ((size_t)t * 50 + (r - 1)) * 1024; }
    }

    if (src == nullptr) {  // pad row: zeros (uniform across block)
        ushort4 z; z.x = z.y = z.z = z.w = 0;
        *reinterpret_cast<ushort4*>(dsth) = z;
        return;
    }

    float4 v = reinterpret_cast<const float4*>(src)[tid];
    v.x += eps_add; v.y += eps_add; v.z += eps_add; v.w += eps_add;
    float ss = v.x * v.x + v.y * v.y + v.z * v.z + v.w * v.w;
    #pragma unroll
    for (int m = 1; m <= 32; m <<= 1) ss += __shfl_xor(ss, m);
    if ((tid & 63) == 0) red[tid >> 6] = ss;
    __syncthreads();
    const float tot = red[0] + red[1] + red[2] + red[3];
    const float rn = 1.0f / sqrtf(tot);

    ushort4 o;
    o.x = __half_as_ushort(__float2half(v.x * rn));
    o.y = __half_as_ushort(__float2half(v.y * rn));
    o.z = __half_as_ushort(__float2half(v.z * rn));
    o.w = __half_as_ushort(__float2half(v.w * rn));
    *reinterpret_cast<ushort4*>(dsth) = o;
}

// ---------------- Phase 2: fused GEMM (BK=64, 16 tiles) + Sinkhorn, 4-wave blocks ----------------
// Block tile 80 A rows (1 img pair) x 128 B cols (2 caps), 256 threads.
// Wave w covers cols w*32..w*32+31 (cap tt = w>>1, col half = w&1); each wave
// computes 80x32 -> acc 5x2 = 40 AGPR.  4 blocks/CU (R12's proven config),
// but 16 K-tiles instead of 32 -> half the per-window fixed overhead.
// A in LDS: THREE 10,240-B buffers (128-B rows), staged 2 tiles ahead;
// swizzle slot = (ks*4+q4) ^ (row&7) (source-permuted, LDS linear) ->
// uniform 8 lanes per 4-bank group, conflict-free.
// B direct global->VGPR (fragment-major), 4 frags/tile, double-buffered
// 2 tiles ahead.  One barrier/tile: stage at kt overwrites the buffer read
// at kt-1 (reads retired at kt-1's lgkm0 + barrier).
// 10 A-octets (8 rows x 1 KB)/tile: wave w takes o=w, w+4 (+ w+8 if w<2)
// -> a = 3 (w 0,1) / 2 (w 2,3).  Steady vmcnt leaves B(kt+1)·4 + A(kt+1)·a.
__device__ __forceinline__ void stage_octA(const __half* __restrict__ Ag,
                                           __half* buf, int kb, int o, size_t lofs) {
    const __half* src = Ag + (size_t)o * 8192 + kb + lofs;   // 8 rows x 1024 halves
    __builtin_amdgcn_global_load_lds((const AS1 void*)src,
                                     (AS3 void*)(buf + o * 512), 16, 0, 0);
}

__device__ __forceinline__ void stage_A(const __half* __restrict__ Ag,
                                        __half* buf, int kb, int wave, size_t lofs) {
    stage_octA(Ag, buf, kb, wave, lofs);
    stage_octA(Ag, buf, kb, wave + 4, lofs);
    if (wave < 2) stage_octA(Ag, buf, kb, wave + 8, lofs);
}

template <int KS>
__device__ __forceinline__ void ds_af(const __half* buf, int fr, int q4,
                                      f16x8 af[5]) {
    const int soff = (((KS * 4 + q4) ^ (fr & 7)) * 8);   // swizzled seg, halves
    #pragma unroll
    for (int m = 0; m < 5; ++m) {
        const int R = m * 16 + fr;
        af[m] = *reinterpret_cast<const f16x8*>(buf + R * BK + soff);
    }
}

__device__ __forceinline__ void load_bf(const __half* __restrict__ Bgw, int kt,
                                        f16x8 bf[4]) {
    const __half* p = Bgw + (size_t)kt * 4096;   // 2 K32-subtiles x 2048 halves
    bf[0] = *reinterpret_cast<const f16x8*>(p);              // ks0, n0
    bf[1] = *reinterpret_cast<const f16x8*>(p + 512);        // ks0, n1
    bf[2] = *reinterpret_cast<const f16x8*>(p + 2048);       // ks1, n0
    bf[3] = *reinterpret_cast<const f16x8*>(p + 2560);       // ks1, n1
}

template <int KS>
__device__ __forceinline__ void mfma_cluster(f32x4 acc[5][2], const f16x8 af[5],
                                             const f16x8 bf[4]) {
    __builtin_amdgcn_s_setprio(1);
    #pragma unroll
    for (int m = 0; m < 5; ++m)
        #pragma unroll
        for (int n = 0; n < 2; ++n)
            acc[m][n] = __builtin_amdgcn_mfma_f32_16x16x32_f16(af[m], bf[KS * 2 + n],
                                                               acc[m][n], 0, 0, 0);
    __builtin_amdgcn_s_setprio(0);
}

__global__ __launch_bounds__(256, 4) void fused_kernel(
        const __half* __restrict__ Ah, const __half* __restrict__ Bh,
        const int* __restrict__ img_lens, const int* __restrict__ cap_lens,
        float* __restrict__ out) {
    __shared__ __align__(16) char smem[SMEM_BYTES];   // 37,888 B -> 4 blocks/CU
    __half* lds0 = reinterpret_cast<__half*>(smem);
    __half* lds1 = reinterpret_cast<__half*>(smem + BUF_BYTES);
    __half* lds2 = reinterpret_cast<__half*>(smem + 2 * BUF_BYTES);

    // XCD-chunked mapping: 8 consecutive blocks share bx across 8 by slices.
    const int idx = blockIdx.x;            // 0..4095
    const int xcd = idx & 7;
    const int within = idx >> 3;           // 0..511
    const int bx = within >> 3;            // 0..63  (A group = img pair)
    const int by = xcd * 8 + (within & 7); // 0..63  (cap pair)

    const int tid = threadIdx.x;
    const int wave = tid >> 6;             // 0..3
    const int lane = tid & 63;
    const int fr = lane & 15;
    const int q4 = lane >> 4;

    const __half* Ag = Ah + (size_t)bx * 80 * 1024;
    // wave's cap t = 2by + (wave>>1); frag base = (wave&1)*2 frags
    const __half* Bgw = Bh + (size_t)(2 * by + (wave >> 1)) * 65536
                           + (size_t)((wave & 1) * 2) * 512 + lane * 8;

    // A staging source: rsub = lane>>3 (row in 8-row octet); stored slot
    // (lane&7) holds global seg (lane&7) ^ rsub.  LDS dest linear.
    const int rsub8 = lane >> 3;
    const int segsrc = (lane & 7) ^ rsub8;
    const size_t lofs = (size_t)rsub8 * 1024 + (size_t)(segsrc * 8);

    f32x4 acc[5][2];
    #pragma unroll
    for (int m = 0; m < 5; ++m)
        #pragma unroll
        for (int n = 0; n < 2; ++n) {
            f32x4 z = {0.0f, 0.0f, 0.0f, 0.0f};
            acc[m][n] = z;
        }

    f16x8 bfA[4], bfB[4];

    // Prologue.  Queue: [B0·4, A0·a, B1·4, A1·a]; wait leaves 4+a -> B0,A0 done.
    load_bf(Bgw, 0, bfA);
    stage_A(Ag, lds0, 0, wave, lofs);
    load_bf(Bgw, 1, bfB);
    stage_A(Ag, lds1, BK, wave, lofs);
    if (wave < 2) { VM_WAIT(7); } else { VM_WAIT(6); }
    __builtin_amdgcn_s_barrier();

    // Tile kt: ds ks0 -> 10 MFMA -> ds ks1 -> 10 MFMA -> load B(kt+2) ->
    // lgkm0 (own reads retired) -> stage A(kt+2) into buf[(kt+2)%3] (read at
    // kt-1; its reads retired at kt-1's lgkm0+barrier) -> vmcnt(4+a)
    // [B(kt+1), A(kt+1) landed] -> barrier.
    #define GEMM_TILE(KT, RD, ST, CUR)                                \
    {                                                                 \
        f16x8 af[5];                                                  \
        ds_af<0>((RD), fr, q4, af);                                   \
        mfma_cluster<0>(acc, af, (CUR));                              \
        ds_af<1>((RD), fr, q4, af);                                   \
        mfma_cluster<1>(acc, af, (CUR));                              \
        load_bf(Bgw, (KT) + 2, (CUR));                                \
        LGKM0();                                                      \
        stage_A(Ag, (ST), ((KT) + 2) * BK, wave, lofs);               \
        if (wave < 2) { VM_WAIT(7); } else { VM_WAIT(6); }            \
        __builtin_amdgcn_s_barrier();                                 \
    }

    #pragma unroll 1
    for (int kt = 0; kt < 12; kt += 6) {
        GEMM_TILE(kt,     lds0, lds2, bfA);
        GEMM_TILE(kt + 1, lds1, lds0, bfB);
        GEMM_TILE(kt + 2, lds2, lds1, bfA);
        GEMM_TILE(kt + 3, lds0, lds2, bfB);
        GEMM_TILE(kt + 4, lds1, lds0, bfA);
        GEMM_TILE(kt + 5, lds2, lds1, bfB);
    }
    GEMM_TILE(12, lds0, lds2, bfA);   // stages A14, loads B14
    GEMM_TILE(13, lds1, lds0, bfB);   // stages A15, loads B15
    #undef GEMM_TILE

    // ---- tile 14 (no staging/loads; A15+B15 in flight) ----
    {
        f16x8 af[5];
        ds_af<0>(lds2, fr, q4, af);
        mfma_cluster<0>(acc, af, bfA);         // B(14), landed at kt=13's wait
        ds_af<1>(lds2, fr, q4, af);
        mfma_cluster<1>(acc, af, bfA);
        LGKM0();
        VM_WAIT(0);                            // A15 + B15 landed
        __builtin_amdgcn_s_barrier();          // A15 visible block-wide
    }
    // ---- tile 15 ----
    {
        f16x8 af[5];
        ds_af<0>(lds0, fr, q4, af);
        mfma_cluster<0>(acc, af, bfB);
        ds_af<1>(lds0, fr, q4, af);
        mfma_cluster<1>(acc, af, bfB);
    }

    __syncthreads();   // staging buffers become fg scratch (block-shared)

    // ---------------- fg scatter: 4 regions of 37x64 f32 (9,472 B each) ----------------
    // Region rg = s*2 + tt covers (img 2bx+s, cap 2by+tt).  Wave w (cap
    // tt = w>>1, col half = w&1) writes rows 0..73 x its 32 cols.
    // Cols XOR-swizzled: col ^ (((sr>>2)&3)<<4) -> Sinkhorn reads conflict-free.
    float* fgall = reinterpret_cast<float*>(smem);
    {
        const int ttw = wave >> 1;
        #pragma unroll
        for (int m = 0; m < 5; ++m) {
            #pragma unroll
            for (int q = 0; q < 4; ++q) {
                const int Rl = m * 16 + q4 * 4 + q;     // 0..79
                const int s = (Rl >= 37) ? 1 : 0;
                const int sr = Rl - 37 * s;             // scratch row
                const bool valid = (Rl < 74);
                const int rg = s * 2 + ttw;
                const int sw = ((sr >> 2) & 3) << 4;
                #pragma unroll
                for (int n = 0; n < 2; ++n) {
                    const int sc = (wave & 1) * 32 + n * 16 + fr;
                    if (valid)
                        fgall[rg * 2368 + sr * 64 + (sc ^ sw)] = acc[m][n][q];
                }
            }
        }
    }
    __syncthreads();   // all 4 regions complete

    // ---------------- Sinkhorn: one task per wave, chunk-skipped + fused DPP ----------------
    // Wave w handles region w: img i = 2bx + (w>>1), cap t = 2by + (w&1).
    {
        float* fg = fgall + wave * 2368;
        const int i = 2 * bx + (wave >> 1);
        const int t = 2 * by + (wave & 1);
        const int il = img_lens[i] + 1;        // 2..37
        const int cl = cap_lens[t] + 1;        // 2..51
        const bool vcol = lane < cl;

        #define FGR(r_) fg[(r_) * 64 + (lane ^ ((((r_) >> 2) & 3) << 4))]
        #define CEND(c_) ((((c_) * 8 + 8) < 37) ? ((c_) * 8 + 8) : 37)

        float P[37];
        #pragma unroll
        for (int r = 0; r < 37; ++r) P[r] = 0.0f;

        float ts[4] = {0.f, 0.f, 0.f, 0.f};
        #pragma unroll
        for (int c = 0; c < 5; ++c) {
            if (c * 8 < il) {                       // wave-uniform chunk skip
                #pragma unroll
                for (int r = c * 8; r < CEND(c); ++r) {
                    const float f = FGR(r);
                    const bool act = (r < il) && vcol;
                    const float pe = act ? __expf((f - 1.0f) * 10.0f) : 0.0f;
                    P[r] = pe;
                    ts[r & 3] += pe;
                }
            }
        }
        float tot = (ts[0] + ts[1]) + (ts[2] + ts[3]);
        tot = wave_sum_fast(tot);
        const float s0 = __builtin_amdgcn_rcpf(tot + EPSF);
        #pragma unroll
        for (int c = 0; c < 5; ++c) {
            if (c * 8 < il) {
                #pragma unroll
                for (int r = c * 8; r < CEND(c); ++r) P[r] *= s0;
            }
        }

        const float rmarg = 1.0f / (float)il;
        const float cmarg = 1.0f / (float)cl;
        float csave = 0.0f;
        for (int it = 0; it < 3; ++it) {
            #pragma unroll
            for (int c = 0; c < 5; ++c) {
                if (c * 8 < il) {
                    #pragma unroll
                    for (int r = c * 8; r < CEND(c); ++r) {   // 8 indep chains
                        const float u = wave_sum_fast(P[r]);
                        P[r] *= rmarg * __builtin_amdgcn_rcpf(u + EPSF);
                    }
                }
            }
            float vs[4] = {EPSF, 0.f, 0.f, 0.f};
            #pragma unroll
            for (int c = 0; c < 5; ++c) {
                if (c * 8 < il) {
                    #pragma unroll
                    for (int r = c * 8; r < CEND(c); ++r) vs[r & 3] += P[r];
                }
            }
            const float v = (vs[0] + vs[1]) + (vs[2] + vs[3]);
            const float cs = vcol ? cmarg * __builtin_amdgcn_rcpf(v) : 0.0f;
            if (it < 2) {
                #pragma unroll
                for (int c = 0; c < 5; ++c) {
                    if (c * 8 < il) {
                        #pragma unroll
                        for (int r = c * 8; r < CEND(c); ++r) P[r] *= cs;
                    }
                }
            } else {
                csave = cs;                               // fold last scale into dot
            }
        }

        float ls[4] = {0.f, 0.f, 0.f, 0.f};
        #pragma unroll
        for (int c = 0; c < 5; ++c) {
            if (c * 8 < il) {
                #pragma unroll
                for (int r = c * 8; r < CEND(c); ++r) {
                    const float f = FGR(r);
                    const float fm = (r < il) ? f : 0.0f;   // mask BEFORE multiply
                    ls[r & 3] = fmaf(fm, P[r], ls[r & 3]);
                }
            }
        }
        float local = csave * ((ls[0] + ls[1]) + (ls[2] + ls[3]));
        local = wave_sum_fast(local);
        if (lane == 0) out[i * 128 + t] = local;
        #undef FGR
        #undef CEND
    }
}

extern "C" void kernel_launch(void* const* d_in, const int* in_sizes, int n_in,
                              void* d_out, int out_size, void* d_ws, size_t ws_size,
                              hipStream_t stream) {
    const float* img_cls  = (const float*)d_in[0];
    const float* imgs     = (const float*)d_in[1];
    const float* cap_cls  = (const float*)d_in[2];
    const float* caps     = (const float*)d_in[3];
    const int*   img_lens = (const int*)d_in[4];
    const int*   cap_lens = (const int*)d_in[5];
    float* out = (float*)d_out;

    __half* Ah = (__half*)d_ws;                          // 64*80*1024 halves = 10.5 MB
    __half* Bh = Ah + (size_t)64 * 80 * 1024;            // 128*64*1024 halves = 16.8 MB

    norm_kernel<<<64 * 80 + 128 * 64, 256, 0, stream>>>(img_cls, imgs, cap_cls, caps, Ah, Bh);
    fused_kernel<<<4096, 256, 0, stream>>>(Ah, Bh, img_lens, cap_lens, out);
}

// Round 15
// 140.862 us; speedup vs baseline: 1.1596x; 1.0437x over previous
//
#include <hip/hip_runtime.h>
#include <hip/hip_fp16.h>

#define EPSF 1e-6f

typedef _Float16 f16x8 __attribute__((ext_vector_type(8)));
typedef float f32x4 __attribute__((ext_vector_type(4)));

#define BK 64                  // K-tile (halves); LDS A row = 128 B (8 x 16B segs)
#define SMEM_BYTES 37888       // 4 fg regions x 37x64 f32 (3 x 10240 A staging aliases front)
#define BUF_BYTES 10240        // A staging: 80 rows x 128 B

#define AS1 __attribute__((address_space(1)))
#define AS3 __attribute__((address_space(3)))

#define VM_WAIT(N) asm volatile("s_waitcnt vmcnt(" #N ")" ::: "memory")
#define LGKM0()    asm volatile("s_waitcnt lgkmcnt(0)" ::: "memory")

// ---------- wave sum -> scalar (SGPR), fused-DPP version ----------
__device__ __forceinline__ float wave_sum_fast(float x) {
    asm volatile(
        "s_nop 1\n\t"
        "v_add_f32 %0, %0, %0 quad_perm:[1,0,3,2] row_mask:0xf bank_mask:0xf bound_ctrl:0\n\t"
        "s_nop 1\n\t"
        "v_add_f32 %0, %0, %0 quad_perm:[2,3,0,1] row_mask:0xf bank_mask:0xf bound_ctrl:0\n\t"
        "s_nop 1\n\t"
        "v_add_f32 %0, %0, %0 row_half_mirror row_mask:0xf bank_mask:0xf bound_ctrl:0\n\t"
        "s_nop 1\n\t"
        "v_add_f32 %0, %0, %0 row_mirror row_mask:0xf bank_mask:0xf bound_ctrl:0\n\t"
        "s_nop 1\n\t"
        "v_add_f32 %0, %0, %0 row_bcast:15 row_mask:0xf bank_mask:0xf bound_ctrl:0\n\t"
        "s_nop 1\n\t"
        "v_add_f32 %0, %0, %0 row_bcast:31 row_mask:0xf bank_mask:0xf bound_ctrl:0"
        : "+v"(x));
    return __int_as_float(__builtin_amdgcn_readlane(__float_as_int(x), 63));
}

// ---------------- Phase 1: prepend cls, +EPS, L2-normalize, store fp16 ----------------
// A: row-major [64 groups][80 rows][1024]; rows 0..36 = img 2g, 37..73 = img 2g+1.
// B: FRAGMENT-MAJOR by K-32 subtile: Bh[((t*32 + k32)*4 + n)*512 + lane*8].
__global__ __launch_bounds__(256) void norm_kernel(
        const float* __restrict__ img_cls, const float* __restrict__ imgs,
        const float* __restrict__ cap_cls, const float* __restrict__ caps,
        __half* __restrict__ Ah, __half* __restrict__ Bh) {
    __shared__ float red[4];
    const int row = blockIdx.x;
    const int tid = threadIdx.x;

    const float* src = nullptr;
    __half* dsth;
    float eps_add = EPSF;
    if (row < 64 * 80) {
        const int g = row / 80, r = row % 80;
        dsth = Ah + (size_t)row * 1024 + tid * 4;
        int i = -1, rr = 0;
        if (r < 37)      { i = 2 * g;     rr = r; }
        else if (r < 74) { i = 2 * g + 1; rr = r - 37; }
        if (i >= 0) {
            if (rr == 0) { src = img_cls + (size_t)i * 1024; eps_add = 0.0f; }
            else         { src = imgs + ((size_t)i * 36 + (rr - 1)) * 1024; }
        }
    } else {
        const int row2 = row - 64 * 80;
        const int t = row2 >> 6, r = row2 & 63;
        const int n = r >> 4, fr = r & 15;
        const int kt = tid >> 3, q4 = (tid >> 1) & 3, j = (tid & 1) * 4;
        dsth = Bh + ((size_t)(t * 32 + kt) * 4 + n) * 512 + (q4 * 16 + fr) * 8 + j;
        if (r == 0)       { src = cap_cls + (size_t)t * 1024; eps_add = 0.0f; }
        else if (r <= 50) { src = caps + ((size_t)t * 50 + (r - 1)) * 1024; }
    }

    if (src == nullptr) {  // pad row: zeros (uniform across block)
        ushort4 z; z.x = z.y = z.z = z.w = 0;
        *reinterpret_cast<ushort4*>(dsth) = z;
        return;
    }

    float4 v = reinterpret_cast<const float4*>(src)[tid];
    v.x += eps_add; v.y += eps_add; v.z += eps_add; v.w += eps_add;
    float ss = v.x * v.x + v.y * v.y + v.z * v.z + v.w * v.w;
    #pragma unroll
    for (int m = 1; m <= 32; m <<= 1) ss += __shfl_xor(ss, m);
    if ((tid & 63) == 0) red[tid >> 6] = ss;
    __syncthreads();
    const float tot = red[0] + red[1] + red[2] + red[3];
    const float rn = 1.0f / sqrtf(tot);

    ushort4 o;
    o.x = __half_as_ushort(__float2half(v.x * rn));
    o.y = __half_as_ushort(__float2half(v.y * rn));
    o.z = __half_as_ushort(__float2half(v.z * rn));
    o.w = __half_as_ushort(__float2half(v.w * rn));
    *reinterpret_cast<ushort4*>(dsth) = o;
}

// ---------------- Phase 2: fused GEMM (BK=64, 16 tiles) + Sinkhorn, 4-wave blocks ----------------
// Block tile 80 A rows (1 img pair) x 128 B cols (2 caps), 256 threads.
// Wave w covers cols w*32..w*32+31; acc 5x2 = 40 AGPR.  4 blocks/CU.
// A in LDS: THREE 10,240-B buffers (128-B rows), staged 2 tiles ahead;
// swizzle slot = (ks*4+q4) ^ (row&7) (source-permuted, LDS linear).
// B: THREE 2-frag register buffers (24 VGPR total, vs R14's 32 which
// spilled past the 64-arch-VGPR bank): consume-then-overwrite rotation
// with period 3.  Tile kt roles (P0=B(kt,ks0), P1=B(kt,ks1),
// P2=B(kt+1,ks0) in flight); issues B(kt+1,ks1)->P0 after ks0-MFMA and
// B(kt+2,ks0)->P1 after ks1-MFMA; next roles = (P2,P0,P1).
// One barrier/tile.  10 A-octets/tile: wave w takes o=w, w+4 (+ w+8 if
// w<2) -> a = 3 / 2.  Tile-end vmcnt leaves [B(kt+2,ks0)·2, A(kt+2)·a]
// = 2+a -> 5 / 4 (drains B(kt+1,ks1) ~half-tile cover, A(kt+1), B(kt+1,ks0)).
__device__ __forceinline__ void stage_octA(const __half* __restrict__ Ag,
                                           __half* buf, int kb, int o, size_t lofs) {
    const __half* src = Ag + (size_t)o * 8192 + kb + lofs;   // 8 rows x 1024 halves
    __builtin_amdgcn_global_load_lds((const AS1 void*)src,
                                     (AS3 void*)(buf + o * 512), 16, 0, 0);
}

__device__ __forceinline__ void stage_A(const __half* __restrict__ Ag,
                                        __half* buf, int kb, int wave, size_t lofs) {
    stage_octA(Ag, buf, kb, wave, lofs);
    stage_octA(Ag, buf, kb, wave + 4, lofs);
    if (wave < 2) stage_octA(Ag, buf, kb, wave + 8, lofs);
}

template <int KS>
__device__ __forceinline__ void ds_af(const __half* buf, int fr, int q4,
                                      f16x8 af[5]) {
    const int soff = (((KS * 4 + q4) ^ (fr & 7)) * 8);   // swizzled seg, halves
    #pragma unroll
    for (int m = 0; m < 5; ++m) {
        const int R = m * 16 + fr;
        af[m] = *reinterpret_cast<const f16x8*>(buf + R * BK + soff);
    }
}

// load one K-32 subtile (2 frags) of this wave's B columns
__device__ __forceinline__ void load_bf2(const __half* __restrict__ Bgw, int k32,
                                         f16x8 bf[2]) {
    const __half* p = Bgw + (size_t)k32 * 2048;   // Bgw has +frag_base+lane*8
    bf[0] = *reinterpret_cast<const f16x8*>(p);
    bf[1] = *reinterpret_cast<const f16x8*>(p + 512);
}

__device__ __forceinline__ void mfma_cluster(f32x4 acc[5][2], const f16x8 af[5],
                                             const f16x8 bf[2]) {
    __builtin_amdgcn_s_setprio(1);
    #pragma unroll
    for (int m = 0; m < 5; ++m)
        #pragma unroll
        for (int n = 0; n < 2; ++n)
            acc[m][n] = __builtin_amdgcn_mfma_f32_16x16x32_f16(af[m], bf[n], acc[m][n], 0, 0, 0);
    __builtin_amdgcn_s_setprio(0);
}

__global__ __launch_bounds__(256, 4) void fused_kernel(
        const __half* __restrict__ Ah, const __half* __restrict__ Bh,
        const int* __restrict__ img_lens, const int* __restrict__ cap_lens,
        float* __restrict__ out) {
    __shared__ __align__(16) char smem[SMEM_BYTES];   // 37,888 B -> 4 blocks/CU
    __half* lds0 = reinterpret_cast<__half*>(smem);
    __half* lds1 = reinterpret_cast<__half*>(smem + BUF_BYTES);
    __half* lds2 = reinterpret_cast<__half*>(smem + 2 * BUF_BYTES);

    // XCD-chunked mapping: 8 consecutive blocks share bx across 8 by slices.
    const int idx = blockIdx.x;            // 0..4095
    const int xcd = idx & 7;
    const int within = idx >> 3;           // 0..511
    const int bx = within >> 3;            // 0..63  (A group = img pair)
    const int by = xcd * 8 + (within & 7); // 0..63  (cap pair)

    const int tid = threadIdx.x;
    const int wave = tid >> 6;             // 0..3
    const int lane = tid & 63;
    const int fr = lane & 15;
    const int q4 = lane >> 4;

    const __half* Ag = Ah + (size_t)bx * 80 * 1024;
    // wave's cap t = 2by + (wave>>1); frag base = (wave&1)*2 frags
    const __half* Bgw = Bh + (size_t)(2 * by + (wave >> 1)) * 65536
                           + (size_t)((wave & 1) * 2) * 512 + lane * 8;

    // A staging source: rsub = lane>>3 (row in 8-row octet); stored slot
    // (lane&7) holds global seg (lane&7) ^ rsub.  LDS dest linear.
    const int rsub8 = lane >> 3;
    const int segsrc = (lane & 7) ^ rsub8;
    const size_t lofs = (size_t)rsub8 * 1024 + (size_t)(segsrc * 8);

    f32x4 acc[5][2];
    #pragma unroll
    for (int m = 0; m < 5; ++m)
        #pragma unroll
        for (int n = 0; n < 2; ++n) {
            f32x4 z = {0.0f, 0.0f, 0.0f, 0.0f};
            acc[m][n] = z;
        }

    f16x8 b0[2], b1[2], b2[2];

    // Prologue.  Queue: [B(0,ks0)·2, B(0,ks1)·2, A0·a, B(1,ks0)·2, A1·a];
    // wait leaves [B(1,ks0)·2, A1·a] = 2+a -> B(0), A0 landed.
    load_bf2(Bgw, 0, b0);
    load_bf2(Bgw, 1, b1);
    stage_A(Ag, lds0, 0, wave, lofs);
    load_bf2(Bgw, 2, b2);
    stage_A(Ag, lds1, BK, wave, lofs);
    if (wave < 2) { VM_WAIT(5); } else { VM_WAIT(4); }
    __builtin_amdgcn_s_barrier();

    // Tile kt: ds ks0 -> MFMA(P0) -> load B(kt+1,ks1)->P0 -> ds ks1 ->
    // MFMA(P1) -> load B(kt+2,ks0)->P1 -> lgkm0 -> stage A(kt+2) into
    // buf[(kt+2)%3] (read at kt-1; reads retired at kt-1's lgkm0+barrier)
    // -> vmcnt(2+a) -> barrier.
    #define GEMM_TILE(KT, RD, ST, P0, P1, P2)                         \
    {                                                                 \
        f16x8 af[5];                                                  \
        ds_af<0>((RD), fr, q4, af);                                   \
        mfma_cluster(acc, af, (P0));                                  \
        load_bf2(Bgw, 2 * (KT) + 3, (P0));                            \
        ds_af<1>((RD), fr, q4, af);                                   \
        mfma_cluster(acc, af, (P1));                                  \
        load_bf2(Bgw, 2 * (KT) + 4, (P1));                            \
        LGKM0();                                                      \
        stage_A(Ag, (ST), ((KT) + 2) * BK, wave, lofs);               \
        if (wave < 2) { VM_WAIT(5); } else { VM_WAIT(4); }            \
        __builtin_amdgcn_s_barrier();                                 \
    }

    #pragma unroll 1
    for (int kt = 0; kt < 12; kt += 3) {
        GEMM_TILE(kt,     lds0, lds2, b0, b1, b2);
        GEMM_TILE(kt + 1, lds1, lds0, b2, b0, b1);
        GEMM_TILE(kt + 2, lds2, lds1, b1, b2, b0);
    }
    GEMM_TILE(12, lds0, lds2, b0, b1, b2);   // stages A14; loads B(13,ks1), B(14,ks0)
    GEMM_TILE(13, lds1, lds0, b2, b0, b1);   // stages A15; loads B(14,ks1), B(15,ks0)
    #undef GEMM_TILE

    // ---- tile 14 (roles b1,b2,b0; no staging) ----
    {
        f16x8 af[5];
        ds_af<0>(lds2, fr, q4, af);
        mfma_cluster(acc, af, b1);             // B(14,ks0)
        load_bf2(Bgw, 31, b1);                 // B(15,ks1)
        ds_af<1>(lds2, fr, q4, af);
        mfma_cluster(acc, af, b2);             // B(14,ks1)
        LGKM0();
        VM_WAIT(0);                            // B(15,*) + A15 landed
        __builtin_amdgcn_s_barrier();          // A15 visible block-wide
    }
    // ---- tile 15 (roles b0,b1) ----
    {
        f16x8 af[5];
        ds_af<0>(lds0, fr, q4, af);
        mfma_cluster(acc, af, b0);             // B(15,ks0)
        ds_af<1>(lds0, fr, q4, af);
        mfma_cluster(acc, af, b1);             // B(15,ks1)
    }

    __syncthreads();   // staging buffers become fg scratch (block-shared)

    // ---------------- fg scatter: 4 regions of 37x64 f32 (9,472 B each) ----------------
    // Region rg = s*2 + tt covers (img 2bx+s, cap 2by+tt).  Wave w (cap
    // tt = w>>1, col half = w&1) writes rows 0..73 x its 32 cols.
    // Cols XOR-swizzled: col ^ (((sr>>2)&3)<<4) -> Sinkhorn reads conflict-free.
    float* fgall = reinterpret_cast<float*>(smem);
    {
        const int ttw = wave >> 1;
        #pragma unroll
        for (int m = 0; m < 5; ++m) {
            #pragma unroll
            for (int q = 0; q < 4; ++q) {
                const int Rl = m * 16 + q4 * 4 + q;     // 0..79
                const int s = (Rl >= 37) ? 1 : 0;
                const int sr = Rl - 37 * s;             // scratch row
                const bool valid = (Rl < 74);
                const int rg = s * 2 + ttw;
                const int sw = ((sr >> 2) & 3) << 4;
                #pragma unroll
                for (int n = 0; n < 2; ++n) {
                    const int sc = (wave & 1) * 32 + n * 16 + fr;
                    if (valid)
                        fgall[rg * 2368 + sr * 64 + (sc ^ sw)] = acc[m][n][q];
                }
            }
        }
    }
    __syncthreads();   // all 4 regions complete

    // ---------------- Sinkhorn: one task per wave, chunk-skipped + fused DPP ----------------
    // Wave w handles region w: img i = 2bx + (w>>1), cap t = 2by + (w&1).
    {
        float* fg = fgall + wave * 2368;
        const int i = 2 * bx + (wave >> 1);
        const int t = 2 * by + (wave & 1);
        const int il = img_lens[i] + 1;        // 2..37
        const int cl = cap_lens[t] + 1;        // 2..51
        const bool vcol = lane < cl;

        #define FGR(r_) fg[(r_) * 64 + (lane ^ ((((r_) >> 2) & 3) << 4))]
        #define CEND(c_) ((((c_) * 8 + 8) < 37) ? ((c_) * 8 + 8) : 37)

        float P[37];
        #pragma unroll
        for (int r = 0; r < 37; ++r) P[r] = 0.0f;

        float ts[4] = {0.f, 0.f, 0.f, 0.f};
        #pragma unroll
        for (int c = 0; c < 5; ++c) {
            if (c * 8 < il) {                       // wave-uniform chunk skip
                #pragma unroll
                for (int r = c * 8; r < CEND(c); ++r) {
                    const float f = FGR(r);
                    const bool act = (r < il) && vcol;
                    const float pe = act ? __expf((f - 1.0f) * 10.0f) : 0.0f;
                    P[r] = pe;
                    ts[r & 3] += pe;
                }
            }
        }
        float tot = (ts[0] + ts[1]) + (ts[2] + ts[3]);
        tot = wave_sum_fast(tot);
        const float s0 = __builtin_amdgcn_rcpf(tot + EPSF);
        #pragma unroll
        for (int c = 0; c < 5; ++c) {
            if (c * 8 < il) {
                #pragma unroll
                for (int r = c * 8; r < CEND(c); ++r) P[r] *= s0;
            }
        }

        const float rmarg = 1.0f / (float)il;
        const float cmarg = 1.0f / (float)cl;
        float csave = 0.0f;
        for (int it = 0; it < 3; ++it) {
            #pragma unroll
            for (int c = 0; c < 5; ++c) {
                if (c * 8 < il) {
                    #pragma unroll
                    for (int r = c * 8; r < CEND(c); ++r) {   // 8 indep chains
                        const float u = wave_sum_fast(P[r]);
                        P[r] *= rmarg * __builtin_amdgcn_rcpf(u + EPSF);
                    }
                }
            }
            float vs[4] = {EPSF, 0.f, 0.f, 0.f};
            #pragma unroll
            for (int c = 0; c < 5; ++c) {
                if (c * 8 < il) {
                    #pragma unroll
                    for (int r = c * 8; r < CEND(c); ++r) vs[r & 3] += P[r];
                }
            }
            const float v = (vs[0] + vs[1]) + (vs[2] + vs[3]);
            const float cs = vcol ? cmarg * __builtin_amdgcn_rcpf(v) : 0.0f;
            if (it < 2) {
                #pragma unroll
                for (int c = 0; c < 5; ++c) {
                    if (c * 8 < il) {
                        #pragma unroll
                        for (int r = c * 8; r < CEND(c); ++r) P[r] *= cs;
                    }
                }
            } else {
                csave = cs;                               // fold last scale into dot
            }
        }

        float ls[4] = {0.f, 0.f, 0.f, 0.f};
        #pragma unroll
        for (int c = 0; c < 5; ++c) {
            if (c * 8 < il) {
                #pragma unroll
                for (int r = c * 8; r < CEND(c); ++r) {
                    const float f = FGR(r);
                    const float fm = (r < il) ? f : 0.0f;   // mask BEFORE multiply
                    ls[r & 3] = fmaf(fm, P[r], ls[r & 3]);
                }
            }
        }
        float local = csave * ((ls[0] + ls[1]) + (ls[2] + ls[3]));
        local = wave_sum_fast(local);
        if (lane == 0) out[i * 128 + t] = local;
        #undef FGR
        #undef CEND
    }
}

extern "C" void kernel_launch(void* const* d_in, const int* in_sizes, int n_in,
                              void* d_out, int out_size, void* d_ws, size_t ws_size,
                              hipStream_t stream) {
    const float* img_cls  = (const float*)d_in[0];
    const float* imgs     = (const float*)d_in[1];
    const float* cap_cls  = (const float*)d_in[2];
    const float* caps     = (const float*)d_in[3];
    const int*   img_lens = (const int*)d_in[4];
    const int*   cap_lens = (const int*)d_in[5];
    float* out = (float*)d_out;

    __half* Ah = (__half*)d_ws;                          // 64*80*1024 halves = 10.5 MB
    __half* Bh = Ah + (size_t)64 * 80 * 1024;            // 128*64*1024 halves = 16.8 MB

    norm_kernel<<<64 * 80 + 128 * 64, 256, 0, stream>>>(img_cls, imgs, cap_cls, caps, Ah, Bh);
    fused_kernel<<<4096, 256, 0, stream>>>(Ah, Bh, img_lens, cap_lens, out);
}

// Round 16
// 138.936 us; speedup vs baseline: 1.1757x; 1.0139x over previous
//
#include <hip/hip_runtime.h>
#include <hip/hip_fp16.h>

#define EPSF 1e-6f

typedef _Float16 f16x8 __attribute__((ext_vector_type(8)));
typedef float f32x4 __attribute__((ext_vector_type(4)));

#define BK 64                  // K-tile (halves); LDS A row = 128 B (8 x 16B segs)
#define SMEM_BYTES 40960       // 4 x 10240 A staging (4 fg regions x 9472 alias inside)
#define BUF_BYTES 10240        // A staging: 80 rows x 128 B

#define AS1 __attribute__((address_space(1)))
#define AS3 __attribute__((address_space(3)))

#define VM_WAIT(N) asm volatile("s_waitcnt vmcnt(" #N ")" ::: "memory")
#define LGKM0()    asm volatile("s_waitcnt lgkmcnt(0)" ::: "memory")

// ---------- wave sum -> scalar (SGPR), fused-DPP version ----------
__device__ __forceinline__ float wave_sum_fast(float x) {
    asm volatile(
        "s_nop 1\n\t"
        "v_add_f32 %0, %0, %0 quad_perm:[1,0,3,2] row_mask:0xf bank_mask:0xf bound_ctrl:0\n\t"
        "s_nop 1\n\t"
        "v_add_f32 %0, %0, %0 quad_perm:[2,3,0,1] row_mask:0xf bank_mask:0xf bound_ctrl:0\n\t"
        "s_nop 1\n\t"
        "v_add_f32 %0, %0, %0 row_half_mirror row_mask:0xf bank_mask:0xf bound_ctrl:0\n\t"
        "s_nop 1\n\t"
        "v_add_f32 %0, %0, %0 row_mirror row_mask:0xf bank_mask:0xf bound_ctrl:0\n\t"
        "s_nop 1\n\t"
        "v_add_f32 %0, %0, %0 row_bcast:15 row_mask:0xf bank_mask:0xf bound_ctrl:0\n\t"
        "s_nop 1\n\t"
        "v_add_f32 %0, %0, %0 row_bcast:31 row_mask:0xf bank_mask:0xf bound_ctrl:0"
        : "+v"(x));
    return __int_as_float(__builtin_amdgcn_readlane(__float_as_int(x), 63));
}

// ---------------- Phase 1: prepend cls, +EPS, L2-normalize, store fp16 ----------------
// A: row-major [64 groups][80 rows][1024]; rows 0..36 = img 2g, 37..73 = img 2g+1.
// B: FRAGMENT-MAJOR by K-32 subtile: Bh[((t*32 + k32)*4 + n)*512 + lane*8].
__global__ __launch_bounds__(256) void norm_kernel(
        const float* __restrict__ img_cls, const float* __restrict__ imgs,
        const float* __restrict__ cap_cls, const float* __restrict__ caps,
        __half* __restrict__ Ah, __half* __restrict__ Bh) {
    __shared__ float red[4];
    const int row = blockIdx.x;
    const int tid = threadIdx.x;

    const float* src = nullptr;
    __half* dsth;
    float eps_add = EPSF;
    if (row < 64 * 80) {
        const int g = row / 80, r = row % 80;
        dsth = Ah + (size_t)row * 1024 + tid * 4;
        int i = -1, rr = 0;
        if (r < 37)      { i = 2 * g;     rr = r; }
        else if (r < 74) { i = 2 * g + 1; rr = r - 37; }
        if (i >= 0) {
            if (rr == 0) { src = img_cls + (size_t)i * 1024; eps_add = 0.0f; }
            else         { src = imgs + ((size_t)i * 36 + (rr - 1)) * 1024; }
        }
    } else {
        const int row2 = row - 64 * 80;
        const int t = row2 >> 6, r = row2 & 63;
        const int n = r >> 4, fr = r & 15;
        const int kt = tid >> 3, q4 = (tid >> 1) & 3, j = (tid & 1) * 4;
        dsth = Bh + ((size_t)(t * 32 + kt) * 4 + n) * 512 + (q4 * 16 + fr) * 8 + j;
        if (r == 0)       { src = cap_cls + (size_t)t * 1024; eps_add = 0.0f; }
        else if (r <= 50) { src = caps + ((size_t)t * 50 + (r - 1)) * 1024; }
    }

    if (src == nullptr) {  // pad row: zeros (uniform across block)
        ushort4 z; z.x = z.y = z.z = z.w = 0;
        *reinterpret_cast<ushort4*>(dsth) = z;
        return;
    }

    float4 v = reinterpret_cast<const float4*>(src)[tid];
    v.x += eps_add; v.y += eps_add; v.z += eps_add; v.w += eps_add;
    float ss = v.x * v.x + v.y * v.y + v.z * v.z + v.w * v.w;
    #pragma unroll
    for (int m = 1; m <= 32; m <<= 1) ss += __shfl_xor(ss, m);
    if ((tid & 63) == 0) red[tid >> 6] = ss;
    __syncthreads();
    const float tot = red[0] + red[1] + red[2] + red[3];
    const float rn = 1.0f / sqrtf(tot);

    ushort4 o;
    o.x = __half_as_ushort(__float2half(v.x * rn));
    o.y = __half_as_ushort(__float2half(v.y * rn));
    o.z = __half_as_ushort(__float2half(v.z * rn));
    o.w = __half_as_ushort(__float2half(v.w * rn));
    *reinterpret_cast<ushort4*>(dsth) = o;
}

// ---------------- Phase 2: fused GEMM (BK=64, 16 tiles, 8 supersteps) + Sinkhorn ----------------
// Block tile 80 A rows x 128 B cols, 256 threads / 4 waves; acc 5x2 = 40 AGPR.
// 4 blocks/CU.  A in LDS: FOUR 10,240-B buffers in two pairs
// (pair0 = L0,L1 ; pair1 = L2,L3).  Superstep s (tiles 2s, 2s+1) reads
// pair (s&1) and stages tiles 2s+2, 2s+3 into the other pair (read at
// superstep s-1; all reads retired at the s-1 boundary lgkm0+barrier).
// ONE barrier per superstep (8 total, vs 16 in the per-tile scheme);
// mid-superstep only a counted vmcnt guards the B rotation.
// B: THREE 2-frag register buffers (24 VGPR), consume-then-overwrite
// rotation by 2 per tile (period 3).  Tile kt issues B(kt+1,ks1) and
// B(kt+2,ks0).  10 A-octets/tile: wave w takes o=w, w+4 (+ w+8 if w<2)
// -> a = 3 / 2.  vmcnt: mid leaves [B(T+2,ks0)·2, A·a, A·a] = 2+2a
// (8/6); end leaves [B(T+3,ks0)·2] = 2.
__device__ __forceinline__ void stage_octA(const __half* __restrict__ Ag,
                                           __half* buf, int kb, int o, size_t lofs) {
    const __half* src = Ag + (size_t)o * 8192 + kb + lofs;   // 8 rows x 1024 halves
    __builtin_amdgcn_global_load_lds((const AS1 void*)src,
                                     (AS3 void*)(buf + o * 512), 16, 0, 0);
}

__device__ __forceinline__ void stage_A(const __half* __restrict__ Ag,
                                        __half* buf, int kb, int wave, size_t lofs) {
    stage_octA(Ag, buf, kb, wave, lofs);
    stage_octA(Ag, buf, kb, wave + 4, lofs);
    if (wave < 2) stage_octA(Ag, buf, kb, wave + 8, lofs);
}

template <int KS>
__device__ __forceinline__ void ds_af(const __half* buf, int fr, int q4,
                                      f16x8 af[5]) {
    const int soff = (((KS * 4 + q4) ^ (fr & 7)) * 8);   // swizzled seg, halves
    #pragma unroll
    for (int m = 0; m < 5; ++m) {
        const int R = m * 16 + fr;
        af[m] = *reinterpret_cast<const f16x8*>(buf + R * BK + soff);
    }
}

// load one K-32 subtile (2 frags) of this wave's B columns
__device__ __forceinline__ void load_bf2(const __half* __restrict__ Bgw, int k32,
                                         f16x8 bf[2]) {
    const __half* p = Bgw + (size_t)k32 * 2048;   // Bgw has +frag_base+lane*8
    bf[0] = *reinterpret_cast<const f16x8*>(p);
    bf[1] = *reinterpret_cast<const f16x8*>(p + 512);
}

__device__ __forceinline__ void mfma_cluster(f32x4 acc[5][2], const f16x8 af[5],
                                             const f16x8 bf[2]) {
    __builtin_amdgcn_s_setprio(1);
    #pragma unroll
    for (int m = 0; m < 5; ++m)
        #pragma unroll
        for (int n = 0; n < 2; ++n)
            acc[m][n] = __builtin_amdgcn_mfma_f32_16x16x32_f16(af[m], bf[n], acc[m][n], 0, 0, 0);
    __builtin_amdgcn_s_setprio(0);
}

__global__ __launch_bounds__(256, 4) void fused_kernel(
        const __half* __restrict__ Ah, const __half* __restrict__ Bh,
        const int* __restrict__ img_lens, const int* __restrict__ cap_lens,
        float* __restrict__ out) {
    __shared__ __align__(16) char smem[SMEM_BYTES];   // 40,960 B x 4 blocks = 160 KiB
    __half* lds0 = reinterpret_cast<__half*>(smem);
    __half* lds1 = reinterpret_cast<__half*>(smem + BUF_BYTES);
    __half* lds2 = reinterpret_cast<__half*>(smem + 2 * BUF_BYTES);
    __half* lds3 = reinterpret_cast<__half*>(smem + 3 * BUF_BYTES);

    // XCD-chunked mapping: 8 consecutive blocks share bx across 8 by slices.
    const int idx = blockIdx.x;            // 0..4095
    const int xcd = idx & 7;
    const int within = idx >> 3;           // 0..511
    const int bx = within >> 3;            // 0..63  (A group = img pair)
    const int by = xcd * 8 + (within & 7); // 0..63  (cap pair)

    const int tid = threadIdx.x;
    const int wave = tid >> 6;             // 0..3
    const int lane = tid & 63;
    const int fr = lane & 15;
    const int q4 = lane >> 4;

    const __half* Ag = Ah + (size_t)bx * 80 * 1024;
    // wave's cap t = 2by + (wave>>1); frag base = (wave&1)*2 frags
    const __half* Bgw = Bh + (size_t)(2 * by + (wave >> 1)) * 65536
                           + (size_t)((wave & 1) * 2) * 512 + lane * 8;

    // A staging source: rsub = lane>>3 (row in 8-row octet); stored slot
    // (lane&7) holds global seg (lane&7) ^ rsub.  LDS dest linear.
    const int rsub8 = lane >> 3;
    const int segsrc = (lane & 7) ^ rsub8;
    const size_t lofs = (size_t)rsub8 * 1024 + (size_t)(segsrc * 8);

    f32x4 acc[5][2];
    #pragma unroll
    for (int m = 0; m < 5; ++m)
        #pragma unroll
        for (int n = 0; n < 2; ++n) {
            f32x4 z = {0.0f, 0.0f, 0.0f, 0.0f};
            acc[m][n] = z;
        }

    f16x8 b0[2], b1[2], b2[2];

    // Prologue.  Queue: [B(0,ks0)·2, B(0,ks1)·2, A0·a, A1·a, B(1,ks0)·2,
    // A2·a, A3·a]; wait leaves 2+2a -> B(0,*), A0, A1 landed.
    load_bf2(Bgw, 0, b0);
    load_bf2(Bgw, 1, b1);
    stage_A(Ag, lds0, 0, wave, lofs);
    stage_A(Ag, lds1, BK, wave, lofs);
    load_bf2(Bgw, 2, b2);
    stage_A(Ag, lds2, 2 * BK, wave, lofs);
    stage_A(Ag, lds3, 3 * BK, wave, lofs);
    if (wave < 2) { VM_WAIT(8); } else { VM_WAIT(6); }
    __builtin_amdgcn_s_barrier();

    // ---- superstep 0 (tiles 0,1; reads L0,L1; no staging) ----
    {
        f16x8 af[5];
        ds_af<0>(lds0, fr, q4, af);
        mfma_cluster(acc, af, b0);             // B(0,ks0)
        load_bf2(Bgw, 3, b0);                  // B(1,ks1)
        ds_af<1>(lds0, fr, q4, af);
        mfma_cluster(acc, af, b1);             // B(0,ks1)
        load_bf2(Bgw, 4, b1);                  // B(2,ks0)
        VM_WAIT(2);                            // k32 2,3 + A2,A3 landed
        ds_af<0>(lds1, fr, q4, af);
        mfma_cluster(acc, af, b2);             // B(1,ks0)
        load_bf2(Bgw, 5, b2);                  // B(2,ks1)
        ds_af<1>(lds1, fr, q4, af);
        mfma_cluster(acc, af, b0);             // B(1,ks1)
        load_bf2(Bgw, 6, b0);                  // B(3,ks0)
        LGKM0();
        VM_WAIT(2);                            // k32 4,5 landed; k32 6 in flight
        __builtin_amdgcn_s_barrier();
    }

    // ---- supersteps 1..6 (tiles 2..13): read pair s&1, stage other pair ----
    #define SSTEP(T, R0, R1, S0, S1, X, Y, Z)                         \
    {                                                                 \
        f16x8 af[5];                                                  \
        ds_af<0>((R0), fr, q4, af);                                   \
        mfma_cluster(acc, af, (X));                                   \
        load_bf2(Bgw, 2 * (T) + 3, (X));                              \
        ds_af<1>((R0), fr, q4, af);                                   \
        mfma_cluster(acc, af, (Y));                                   \
        load_bf2(Bgw, 2 * (T) + 4, (Y));                              \
        stage_A(Ag, (S0), ((T) + 2) * BK, wave, lofs);                \
        stage_A(Ag, (S1), ((T) + 3) * BK, wave, lofs);                \
        if (wave < 2) { VM_WAIT(8); } else { VM_WAIT(6); }            \
        ds_af<0>((R1), fr, q4, af);                                   \
        mfma_cluster(acc, af, (Z));                                   \
        load_bf2(Bgw, 2 * (T) + 5, (Z));                              \
        ds_af<1>((R1), fr, q4, af);                                   \
        mfma_cluster(acc, af, (X));                                   \
        load_bf2(Bgw, 2 * (T) + 6, (X));                              \
        LGKM0();                                                      \
        VM_WAIT(2);                                                   \
        __builtin_amdgcn_s_barrier();                                 \
    }

    SSTEP(2,  lds2, lds3, lds0, lds1, b1, b2, b0);   // s=1
    SSTEP(4,  lds0, lds1, lds2, lds3, b2, b0, b1);   // s=2
    SSTEP(6,  lds2, lds3, lds0, lds1, b0, b1, b2);   // s=3
    SSTEP(8,  lds0, lds1, lds2, lds3, b1, b2, b0);   // s=4
    SSTEP(10, lds2, lds3, lds0, lds1, b2, b0, b1);   // s=5
    SSTEP(12, lds0, lds1, lds2, lds3, b0, b1, b2);   // s=6: stages A14,A15 -> L2,L3
    #undef SSTEP

    // ---- superstep 7 (tiles 14,15; reads L2,L3; no staging/barrier) ----
    {
        f16x8 af[5];
        ds_af<0>(lds2, fr, q4, af);
        mfma_cluster(acc, af, b1);             // B(14,ks0) = k32 28
        load_bf2(Bgw, 31, b1);                 // B(15,ks1)
        ds_af<1>(lds2, fr, q4, af);
        mfma_cluster(acc, af, b2);             // B(14,ks1) = k32 29
        VM_WAIT(0);                            // k32 30, 31 landed
        ds_af<0>(lds3, fr, q4, af);
        mfma_cluster(acc, af, b0);             // B(15,ks0) = k32 30
        ds_af<1>(lds3, fr, q4, af);
        mfma_cluster(acc, af, b1);             // B(15,ks1) = k32 31
    }

    __syncthreads();   // staging buffers become fg scratch (block-shared)

    // ---------------- fg scatter: 4 regions of 37x64 f32 (9,472 B each) ----------------
    // Region rg = s*2 + tt covers (img 2bx+s, cap 2by+tt).  Wave w (cap
    // tt = w>>1, col half = w&1) writes rows 0..73 x its 32 cols.
    // Cols XOR-swizzled: col ^ (((sr>>2)&3)<<4) -> Sinkhorn reads conflict-free.
    float* fgall = reinterpret_cast<float*>(smem);
    {
        const int ttw = wave >> 1;
        #pragma unroll
        for (int m = 0; m < 5; ++m) {
            #pragma unroll
            for (int q = 0; q < 4; ++q) {
                const int Rl = m * 16 + q4 * 4 + q;     // 0..79
                const int s = (Rl >= 37) ? 1 : 0;
                const int sr = Rl - 37 * s;             // scratch row
                const bool valid = (Rl < 74);
                const int rg = s * 2 + ttw;
                const int sw = ((sr >> 2) & 3) << 4;
                #pragma unroll
                for (int n = 0; n < 2; ++n) {
                    const int sc = (wave & 1) * 32 + n * 16 + fr;
                    if (valid)
                        fgall[rg * 2368 + sr * 64 + (sc ^ sw)] = acc[m][n][q];
                }
            }
        }
    }
    __syncthreads();   // all 4 regions complete

    // ---------------- Sinkhorn: one task per wave, chunk-skipped + fused DPP ----------------
    // Wave w handles region w: img i = 2bx + (w>>1), cap t = 2by + (w&1).
    {
        float* fg = fgall + wave * 2368;
        const int i = 2 * bx + (wave >> 1);
        const int t = 2 * by + (wave & 1);
        const int il = img_lens[i] + 1;        // 2..37
        const int cl = cap_lens[t] + 1;        // 2..51
        const bool vcol = lane < cl;

        #define FGR(r_) fg[(r_) * 64 + (lane ^ ((((r_) >> 2) & 3) << 4))]
        #define CEND(c_) ((((c_) * 8 + 8) < 37) ? ((c_) * 8 + 8) : 37)

        float P[37];
        #pragma unroll
        for (int r = 0; r < 37; ++r) P[r] = 0.0f;

        float ts[4] = {0.f, 0.f, 0.f, 0.f};
        #pragma unroll
        for (int c = 0; c < 5; ++c) {
            if (c * 8 < il) {                       // wave-uniform chunk skip
                #pragma unroll
                for (int r = c * 8; r < CEND(c); ++r) {
                    const float f = FGR(r);
                    const bool act = (r < il) && vcol;
                    const float pe = act ? __expf((f - 1.0f) * 10.0f) : 0.0f;
                    P[r] = pe;
                    ts[r & 3] += pe;
                }
            }
        }
        float tot = (ts[0] + ts[1]) + (ts[2] + ts[3]);
        tot = wave_sum_fast(tot);
        const float s0 = __builtin_amdgcn_rcpf(tot + EPSF);
        #pragma unroll
        for (int c = 0; c < 5; ++c) {
            if (c * 8 < il) {
                #pragma unroll
                for (int r = c * 8; r < CEND(c); ++r) P[r] *= s0;
            }
        }

        const float rmarg = 1.0f / (float)il;
        const float cmarg = 1.0f / (float)cl;
        float csave = 0.0f;
        for (int it = 0; it < 3; ++it) {
            #pragma unroll
            for (int c = 0; c < 5; ++c) {
                if (c * 8 < il) {
                    #pragma unroll
                    for (int r = c * 8; r < CEND(c); ++r) {   // 8 indep chains
                        const float u = wave_sum_fast(P[r]);
                        P[r] *= rmarg * __builtin_amdgcn_rcpf(u + EPSF);
                    }
                }
            }
            float vs[4] = {EPSF, 0.f, 0.f, 0.f};
            #pragma unroll
            for (int c = 0; c < 5; ++c) {
                if (c * 8 < il) {
                    #pragma unroll
                    for (int r = c * 8; r < CEND(c); ++r) vs[r & 3] += P[r];
                }
            }
            const float v = (vs[0] + vs[1]) + (vs[2] + vs[3]);
            const float cs = vcol ? cmarg * __builtin_amdgcn_rcpf(v) : 0.0f;
            if (it < 2) {
                #pragma unroll
                for (int c = 0; c < 5; ++c) {
                    if (c * 8 < il) {
                        #pragma unroll
                        for (int r = c * 8; r < CEND(c); ++r) P[r] *= cs;
                    }
                }
            } else {
                csave = cs;                               // fold last scale into dot
            }
        }

        float ls[4] = {0.f, 0.f, 0.f, 0.f};
        #pragma unroll
        for (int c = 0; c < 5; ++c) {
            if (c * 8 < il) {
                #pragma unroll
                for (int r = c * 8; r < CEND(c); ++r) {
                    const float f = FGR(r);
                    const float fm = (r < il) ? f : 0.0f;   // mask BEFORE multiply
                    ls[r & 3] = fmaf(fm, P[r], ls[r & 3]);
                }
            }
        }
        float local = csave * ((ls[0] + ls[1]) + (ls[2] + ls[3]));
        local = wave_sum_fast(local);
        if (lane == 0) out[i * 128 + t] = local;
        #undef FGR
        #undef CEND
    }
}

extern "C" void kernel_launch(void* const* d_in, const int* in_sizes, int n_in,
                              void* d_out, int out_size, void* d_ws, size_t ws_size,
                              hipStream_t stream) {
    const float* img_cls  = (const float*)d_in[0];
    const float* imgs     = (const float*)d_in[1];
    const float* cap_cls  = (const float*)d_in[2];
    const float* caps     = (const float*)d_in[3];
    const int*   img_lens = (const int*)d_in[4];
    const int*   cap_lens = (const int*)d_in[5];
    float* out = (float*)d_out;

    __half* Ah = (__half*)d_ws;                          // 64*80*1024 halves = 10.5 MB
    __half* Bh = Ah + (size_t)64 * 80 * 1024;            // 128*64*1024 halves = 16.8 MB

    norm_kernel<<<64 * 80 + 128 * 64, 256, 0, stream>>>(img_cls, imgs, cap_cls, caps, Ah, Bh);
    fused_kernel<<<4096, 256, 0, stream>>>(Ah, Bh, img_lens, cap_lens, out);
}

// Round 17
// 135.041 us; speedup vs baseline: 1.2096x; 1.0288x over previous
//
#include <hip/hip_runtime.h>
#include <hip/hip_fp16.h>

#define EPSF 1e-6f

typedef _Float16 f16x8 __attribute__((ext_vector_type(8)));
typedef float f32x4 __attribute__((ext_vector_type(4)));

#define BK 64                  // K-tile (halves); LDS A row = 128 B (8 x 16B segs)
#define SMEM_BYTES 40960       // 4 x 10240 A staging (4 fg regions x 9472 alias inside)
#define BUF_BYTES 10240        // A staging: 80 rows x 128 B

#define AS1 __attribute__((address_space(1)))
#define AS3 __attribute__((address_space(3)))

#define VM_WAIT(N) asm volatile("s_waitcnt vmcnt(" #N ")" ::: "memory")
#define LGKM0()    asm volatile("s_waitcnt lgkmcnt(0)" ::: "memory")

// ---------- wave sum -> scalar (SGPR), fused-DPP version ----------
// Single chain: 6 dependent DPP adds; each needs 2 wait-states after its
// producer -> s_nop 1 between stages (half the issue slots are bubbles).
__device__ __forceinline__ float wave_sum_fast(float x) {
    asm volatile(
        "s_nop 1\n\t"
        "v_add_f32 %0, %0, %0 quad_perm:[1,0,3,2] row_mask:0xf bank_mask:0xf bound_ctrl:0\n\t"
        "s_nop 1\n\t"
        "v_add_f32 %0, %0, %0 quad_perm:[2,3,0,1] row_mask:0xf bank_mask:0xf bound_ctrl:0\n\t"
        "s_nop 1\n\t"
        "v_add_f32 %0, %0, %0 row_half_mirror row_mask:0xf bank_mask:0xf bound_ctrl:0\n\t"
        "s_nop 1\n\t"
        "v_add_f32 %0, %0, %0 row_mirror row_mask:0xf bank_mask:0xf bound_ctrl:0\n\t"
        "s_nop 1\n\t"
        "v_add_f32 %0, %0, %0 row_bcast:15 row_mask:0xf bank_mask:0xf bound_ctrl:0\n\t"
        "s_nop 1\n\t"
        "v_add_f32 %0, %0, %0 row_bcast:31 row_mask:0xf bank_mask:0xf bound_ctrl:0"
        : "+v"(x));
    return __int_as_float(__builtin_amdgcn_readlane(__float_as_int(x), 63));
}

// TWO chains interleaved in ONE asm block: chain B's stage-k add sits
// between chain A's stage-k and stage-k+1 — one wave64 VALU op = 2 issue
// cycles = exactly the required 2 DPP wait-states, so no s_nops at all.
// Both sums complete in the issue time one serial chain used to take.
// (asm volatile blocks can't be compiler-interleaved, hence manual fusion.)
__device__ __forceinline__ void wave_sum2(float& x0, float& x1) {
    asm volatile(
        "s_nop 1\n\t"
        "v_add_f32 %0, %0, %0 quad_perm:[1,0,3,2] row_mask:0xf bank_mask:0xf bound_ctrl:0\n\t"
        "v_add_f32 %1, %1, %1 quad_perm:[1,0,3,2] row_mask:0xf bank_mask:0xf bound_ctrl:0\n\t"
        "v_add_f32 %0, %0, %0 quad_perm:[2,3,0,1] row_mask:0xf bank_mask:0xf bound_ctrl:0\n\t"
        "v_add_f32 %1, %1, %1 quad_perm:[2,3,0,1] row_mask:0xf bank_mask:0xf bound_ctrl:0\n\t"
        "v_add_f32 %0, %0, %0 row_half_mirror row_mask:0xf bank_mask:0xf bound_ctrl:0\n\t"
        "v_add_f32 %1, %1, %1 row_half_mirror row_mask:0xf bank_mask:0xf bound_ctrl:0\n\t"
        "v_add_f32 %0, %0, %0 row_mirror row_mask:0xf bank_mask:0xf bound_ctrl:0\n\t"
        "v_add_f32 %1, %1, %1 row_mirror row_mask:0xf bank_mask:0xf bound_ctrl:0\n\t"
        "v_add_f32 %0, %0, %0 row_bcast:15 row_mask:0xf bank_mask:0xf bound_ctrl:0\n\t"
        "v_add_f32 %1, %1, %1 row_bcast:15 row_mask:0xf bank_mask:0xf bound_ctrl:0\n\t"
        "v_add_f32 %0, %0, %0 row_bcast:31 row_mask:0xf bank_mask:0xf bound_ctrl:0\n\t"
        "v_add_f32 %1, %1, %1 row_bcast:31 row_mask:0xf bank_mask:0xf bound_ctrl:0"
        : "+v"(x0), "+v"(x1));
    x0 = __int_as_float(__builtin_amdgcn_readlane(__float_as_int(x0), 63));
    x1 = __int_as_float(__builtin_amdgcn_readlane(__float_as_int(x1), 63));
}

// ---------------- Phase 1: prepend cls, +EPS, L2-normalize, store fp16 ----------------
// A: row-major [64 groups][80 rows][1024]; rows 0..36 = img 2g, 37..73 = img 2g+1.
// B: FRAGMENT-MAJOR by K-32 subtile: Bh[((t*32 + k32)*4 + n)*512 + lane*8].
__global__ __launch_bounds__(256) void norm_kernel(
        const float* __restrict__ img_cls, const float* __restrict__ imgs,
        const float* __restrict__ cap_cls, const float* __restrict__ caps,
        __half* __restrict__ Ah, __half* __restrict__ Bh) {
    __shared__ float red[4];
    const int row = blockIdx.x;
    const int tid = threadIdx.x;

    const float* src = nullptr;
    __half* dsth;
    float eps_add = EPSF;
    if (row < 64 * 80) {
        const int g = row / 80, r = row % 80;
        dsth = Ah + (size_t)row * 1024 + tid * 4;
        int i = -1, rr = 0;
        if (r < 37)      { i = 2 * g;     rr = r; }
        else if (r < 74) { i = 2 * g + 1; rr = r - 37; }
        if (i >= 0) {
            if (rr == 0) { src = img_cls + (size_t)i * 1024; eps_add = 0.0f; }
            else         { src = imgs + ((size_t)i * 36 + (rr - 1)) * 1024; }
        }
    } else {
        const int row2 = row - 64 * 80;
        const int t = row2 >> 6, r = row2 & 63;
        const int n = r >> 4, fr = r & 15;
        const int kt = tid >> 3, q4 = (tid >> 1) & 3, j = (tid & 1) * 4;
        dsth = Bh + ((size_t)(t * 32 + kt) * 4 + n) * 512 + (q4 * 16 + fr) * 8 + j;
        if (r == 0)       { src = cap_cls + (size_t)t * 1024; eps_add = 0.0f; }
        else if (r <= 50) { src = caps + ((size_t)t * 50 + (r - 1)) * 1024; }
    }

    if (src == nullptr) {  // pad row: zeros (uniform across block)
        ushort4 z; z.x = z.y = z.z = z.w = 0;
        *reinterpret_cast<ushort4*>(dsth) = z;
        return;
    }

    float4 v = reinterpret_cast<const float4*>(src)[tid];
    v.x += eps_add; v.y += eps_add; v.z += eps_add; v.w += eps_add;
    float ss = v.x * v.x + v.y * v.y + v.z * v.z + v.w * v.w;
    #pragma unroll
    for (int m = 1; m <= 32; m <<= 1) ss += __shfl_xor(ss, m);
    if ((tid & 63) == 0) red[tid >> 6] = ss;
    __syncthreads();
    const float tot = red[0] + red[1] + red[2] + red[3];
    const float rn = 1.0f / sqrtf(tot);

    ushort4 o;
    o.x = __half_as_ushort(__float2half(v.x * rn));
    o.y = __half_as_ushort(__float2half(v.y * rn));
    o.z = __half_as_ushort(__float2half(v.z * rn));
    o.w = __half_as_ushort(__float2half(v.w * rn));
    *reinterpret_cast<ushort4*>(dsth) = o;
}

// ---------------- Phase 2: fused GEMM (BK=64, 16 tiles, 8 supersteps) + Sinkhorn ----------------
// Block tile 80 A rows x 128 B cols, 256 threads / 4 waves; acc 5x2 = 40 AGPR.
// 4 blocks/CU.  A in LDS: FOUR 10,240-B buffers in two pairs
// (pair0 = L0,L1 ; pair1 = L2,L3).  Superstep s (tiles 2s, 2s+1) reads
// pair (s&1) and stages tiles 2s+2, 2s+3 into the other pair (read at
// superstep s-1; all reads retired at the s-1 boundary lgkm0+barrier).
// ONE barrier per superstep (8 total); mid-superstep only a counted vmcnt.
// B: THREE 2-frag register buffers (24 VGPR), consume-then-overwrite
// rotation by 2 per tile (period 3).  10 A-octets/tile: wave w takes
// o=w, w+4 (+ w+8 if w<2) -> a = 3 / 2.  vmcnt: mid leaves 2+2a (8/6);
// end leaves 2.
__device__ __forceinline__ void stage_octA(const __half* __restrict__ Ag,
                                           __half* buf, int kb, int o, size_t lofs) {
    const __half* src = Ag + (size_t)o * 8192 + kb + lofs;   // 8 rows x 1024 halves
    __builtin_amdgcn_global_load_lds((const AS1 void*)src,
                                     (AS3 void*)(buf + o * 512), 16, 0, 0);
}

__device__ __forceinline__ void stage_A(const __half* __restrict__ Ag,
                                        __half* buf, int kb, int wave, size_t lofs) {
    stage_octA(Ag, buf, kb, wave, lofs);
    stage_octA(Ag, buf, kb, wave + 4, lofs);
    if (wave < 2) stage_octA(Ag, buf, kb, wave + 8, lofs);
}

template <int KS>
__device__ __forceinline__ void ds_af(const __half* buf, int fr, int q4,
                                      f16x8 af[5]) {
    const int soff = (((KS * 4 + q4) ^ (fr & 7)) * 8);   // swizzled seg, halves
    #pragma unroll
    for (int m = 0; m < 5; ++m) {
        const int R = m * 16 + fr;
        af[m] = *reinterpret_cast<const f16x8*>(buf + R * BK + soff);
    }
}

// load one K-32 subtile (2 frags) of this wave's B columns
__device__ __forceinline__ void load_bf2(const __half* __restrict__ Bgw, int k32,
                                         f16x8 bf[2]) {
    const __half* p = Bgw + (size_t)k32 * 2048;   // Bgw has +frag_base+lane*8
    bf[0] = *reinterpret_cast<const f16x8*>(p);
    bf[1] = *reinterpret_cast<const f16x8*>(p + 512);
}

__device__ __forceinline__ void mfma_cluster(f32x4 acc[5][2], const f16x8 af[5],
                                             const f16x8 bf[2]) {
    __builtin_amdgcn_s_setprio(1);
    #pragma unroll
    for (int m = 0; m < 5; ++m)
        #pragma unroll
        for (int n = 0; n < 2; ++n)
            acc[m][n] = __builtin_amdgcn_mfma_f32_16x16x32_f16(af[m], bf[n], acc[m][n], 0, 0, 0);
    __builtin_amdgcn_s_setprio(0);
}

__global__ __launch_bounds__(256, 4) void fused_kernel(
        const __half* __restrict__ Ah, const __half* __restrict__ Bh,
        const int* __restrict__ img_lens, const int* __restrict__ cap_lens,
        float* __restrict__ out) {
    __shared__ __align__(16) char smem[SMEM_BYTES];   // 40,960 B x 4 blocks = 160 KiB
    __half* lds0 = reinterpret_cast<__half*>(smem);
    __half* lds1 = reinterpret_cast<__half*>(smem + BUF_BYTES);
    __half* lds2 = reinterpret_cast<__half*>(smem + 2 * BUF_BYTES);
    __half* lds3 = reinterpret_cast<__half*>(smem + 3 * BUF_BYTES);

    // XCD-chunked mapping: 8 consecutive blocks share bx across 8 by slices.
    const int idx = blockIdx.x;            // 0..4095
    const int xcd = idx & 7;
    const int within = idx >> 3;           // 0..511
    const int bx = within >> 3;            // 0..63  (A group = img pair)
    const int by = xcd * 8 + (within & 7); // 0..63  (cap pair)

    const int tid = threadIdx.x;
    const int wave = tid >> 6;             // 0..3
    const int lane = tid & 63;
    const int fr = lane & 15;
    const int q4 = lane >> 4;

    const __half* Ag = Ah + (size_t)bx * 80 * 1024;
    // wave's cap t = 2by + (wave>>1); frag base = (wave&1)*2 frags
    const __half* Bgw = Bh + (size_t)(2 * by + (wave >> 1)) * 65536
                           + (size_t)((wave & 1) * 2) * 512 + lane * 8;

    // A staging source: rsub = lane>>3 (row in 8-row octet); stored slot
    // (lane&7) holds global seg (lane&7) ^ rsub.  LDS dest linear.
    const int rsub8 = lane >> 3;
    const int segsrc = (lane & 7) ^ rsub8;
    const size_t lofs = (size_t)rsub8 * 1024 + (size_t)(segsrc * 8);

    f32x4 acc[5][2];
    #pragma unroll
    for (int m = 0; m < 5; ++m)
        #pragma unroll
        for (int n = 0; n < 2; ++n) {
            f32x4 z = {0.0f, 0.0f, 0.0f, 0.0f};
            acc[m][n] = z;
        }

    f16x8 b0[2], b1[2], b2[2];

    // Prologue.  Queue: [B(0,ks0)·2, B(0,ks1)·2, A0·a, A1·a, B(1,ks0)·2,
    // A2·a, A3·a]; wait leaves 2+2a -> B(0,*), A0, A1 landed.
    load_bf2(Bgw, 0, b0);
    load_bf2(Bgw, 1, b1);
    stage_A(Ag, lds0, 0, wave, lofs);
    stage_A(Ag, lds1, BK, wave, lofs);
    load_bf2(Bgw, 2, b2);
    stage_A(Ag, lds2, 2 * BK, wave, lofs);
    stage_A(Ag, lds3, 3 * BK, wave, lofs);
    if (wave < 2) { VM_WAIT(8); } else { VM_WAIT(6); }
    __builtin_amdgcn_s_barrier();

    // ---- superstep 0 (tiles 0,1; reads L0,L1; no staging) ----
    {
        f16x8 af[5];
        ds_af<0>(lds0, fr, q4, af);
        mfma_cluster(acc, af, b0);             // B(0,ks0)
        load_bf2(Bgw, 3, b0);                  // B(1,ks1)
        ds_af<1>(lds0, fr, q4, af);
        mfma_cluster(acc, af, b1);             // B(0,ks1)
        load_bf2(Bgw, 4, b1);                  // B(2,ks0)
        VM_WAIT(2);                            // k32 2,3 + A2,A3 landed
        ds_af<0>(lds1, fr, q4, af);
        mfma_cluster(acc, af, b2);             // B(1,ks0)
        load_bf2(Bgw, 5, b2);                  // B(2,ks1)
        ds_af<1>(lds1, fr, q4, af);
        mfma_cluster(acc, af, b0);             // B(1,ks1)
        load_bf2(Bgw, 6, b0);                  // B(3,ks0)
        LGKM0();
        VM_WAIT(2);                            // k32 4,5 landed; k32 6 in flight
        __builtin_amdgcn_s_barrier();
    }

    // ---- supersteps 1..6 (tiles 2..13): read pair s&1, stage other pair ----
    #define SSTEP(T, R0, R1, S0, S1, X, Y, Z)                         \
    {                                                                 \
        f16x8 af[5];                                                  \
        ds_af<0>((R0), fr, q4, af);                                   \
        mfma_cluster(acc, af, (X));                                   \
        load_bf2(Bgw, 2 * (T) + 3, (X));                              \
        ds_af<1>((R0), fr, q4, af);                                   \
        mfma_cluster(acc, af, (Y));                                   \
        load_bf2(Bgw, 2 * (T) + 4, (Y));                              \
        stage_A(Ag, (S0), ((T) + 2) * BK, wave, lofs);                \
        stage_A(Ag, (S1), ((T) + 3) * BK, wave, lofs);                \
        if (wave < 2) { VM_WAIT(8); } else { VM_WAIT(6); }            \
        ds_af<0>((R1), fr, q4, af);                                   \
        mfma_cluster(acc, af, (Z));                                   \
        load_bf2(Bgw, 2 * (T) + 5, (Z));                              \
        ds_af<1>((R1), fr, q4, af);                                   \
        mfma_cluster(acc, af, (X));                                   \
        load_bf2(Bgw, 2 * (T) + 6, (X));                              \
        LGKM0();                                                      \
        VM_WAIT(2);                                                   \
        __builtin_amdgcn_s_barrier();                                 \
    }

    SSTEP(2,  lds2, lds3, lds0, lds1, b1, b2, b0);   // s=1
    SSTEP(4,  lds0, lds1, lds2, lds3, b2, b0, b1);   // s=2
    SSTEP(6,  lds2, lds3, lds0, lds1, b0, b1, b2);   // s=3
    SSTEP(8,  lds0, lds1, lds2, lds3, b1, b2, b0);   // s=4
    SSTEP(10, lds2, lds3, lds0, lds1, b2, b0, b1);   // s=5
    SSTEP(12, lds0, lds1, lds2, lds3, b0, b1, b2);   // s=6: stages A14,A15 -> L2,L3
    #undef SSTEP

    // ---- superstep 7 (tiles 14,15; reads L2,L3; no staging/barrier) ----
    {
        f16x8 af[5];
        ds_af<0>(lds2, fr, q4, af);
        mfma_cluster(acc, af, b1);             // B(14,ks0) = k32 28
        load_bf2(Bgw, 31, b1);                 // B(15,ks1)
        ds_af<1>(lds2, fr, q4, af);
        mfma_cluster(acc, af, b2);             // B(14,ks1) = k32 29
        VM_WAIT(0);                            // k32 30, 31 landed
        ds_af<0>(lds3, fr, q4, af);
        mfma_cluster(acc, af, b0);             // B(15,ks0) = k32 30
        ds_af<1>(lds3, fr, q4, af);
        mfma_cluster(acc, af, b1);             // B(15,ks1) = k32 31
    }

    __syncthreads();   // staging buffers become fg scratch (block-shared)

    // ---------------- fg scatter: 4 regions of 37x64 f32 (9,472 B each) ----------------
    // Region rg = s*2 + tt covers (img 2bx+s, cap 2by+tt).  Wave w (cap
    // tt = w>>1, col half = w&1) writes rows 0..73 x its 32 cols.
    // Cols XOR-swizzled: col ^ (((sr>>2)&3)<<4) -> Sinkhorn reads conflict-free.
    float* fgall = reinterpret_cast<float*>(smem);
    {
        const int ttw = wave >> 1;
        #pragma unroll
        for (int m = 0; m < 5; ++m) {
            #pragma unroll
            for (int q = 0; q < 4; ++q) {
                const int Rl = m * 16 + q4 * 4 + q;     // 0..79
                const int s = (Rl >= 37) ? 1 : 0;
                const int sr = Rl - 37 * s;             // scratch row
                const bool valid = (Rl < 74);
                const int rg = s * 2 + ttw;
                const int sw = ((sr >> 2) & 3) << 4;
                #pragma unroll
                for (int n = 0; n < 2; ++n) {
                    const int sc = (wave & 1) * 32 + n * 16 + fr;
                    if (valid)
                        fgall[rg * 2368 + sr * 64 + (sc ^ sw)] = acc[m][n][q];
                }
            }
        }
    }
    __syncthreads();   // all 4 regions complete

    // ---------------- Sinkhorn: one task per wave, chunk-skipped + paired DPP ----------------
    // Wave w handles region w: img i = 2bx + (w>>1), cap t = 2by + (w&1).
    // Row-rescales processed in PAIRS via wave_sum2 (interleaved chains,
    // zero s_nops) -- halves the dominant VALU cost of the rescale loop.
    {
        float* fg = fgall + wave * 2368;
        const int i = 2 * bx + (wave >> 1);
        const int t = 2 * by + (wave & 1);
        const int il = img_lens[i] + 1;        // 2..37
        const int cl = cap_lens[t] + 1;        // 2..51
        const bool vcol = lane < cl;

        #define FGR(r_) fg[(r_) * 64 + (lane ^ ((((r_) >> 2) & 3) << 4))]
        #define CEND(c_) ((((c_) * 8 + 8) < 37) ? ((c_) * 8 + 8) : 37)

        float P[37];
        #pragma unroll
        for (int r = 0; r < 37; ++r) P[r] = 0.0f;

        float ts[4] = {0.f, 0.f, 0.f, 0.f};
        #pragma unroll
        for (int c = 0; c < 5; ++c) {
            if (c * 8 < il) {                       // wave-uniform chunk skip
                #pragma unroll
                for (int r = c * 8; r < CEND(c); ++r) {
                    const float f = FGR(r);
                    const bool act = (r < il) && vcol;
                    const float pe = act ? __expf((f - 1.0f) * 10.0f) : 0.0f;
                    P[r] = pe;
                    ts[r & 3] += pe;
                }
            }
        }
        float tot = (ts[0] + ts[1]) + (ts[2] + ts[3]);
        tot = wave_sum_fast(tot);
        const float s0 = __builtin_amdgcn_rcpf(tot + EPSF);
        #pragma unroll
        for (int c = 0; c < 5; ++c) {
            if (c * 8 < il) {
                #pragma unroll
                for (int r = c * 8; r < CEND(c); ++r) P[r] *= s0;
            }
        }

        const float rmarg = 1.0f / (float)il;
        const float cmarg = 1.0f / (float)cl;
        float csave = 0.0f;
        for (int it = 0; it < 3; ++it) {
            #pragma unroll
            for (int c = 0; c < 5; ++c) {
                if (c * 8 < il) {                   // wave-uniform chunk skip
                    #pragma unroll
                    for (int r = c * 8; r < CEND(c); r += 2) {
                        if (r + 1 < CEND(c)) {      // paired: interleaved chains
                            float u0 = P[r], u1 = P[r + 1];
                            wave_sum2(u0, u1);
                            P[r]     *= rmarg * __builtin_amdgcn_rcpf(u0 + EPSF);
                            P[r + 1] *= rmarg * __builtin_amdgcn_rcpf(u1 + EPSF);
                        } else {                    // odd tail row (r = 36)
                            const float u = wave_sum_fast(P[r]);
                            P[r] *= rmarg * __builtin_amdgcn_rcpf(u + EPSF);
                        }
                    }
                }
            }
            float vs[4] = {EPSF, 0.f, 0.f, 0.f};
            #pragma unroll
            for (int c = 0; c < 5; ++c) {
                if (c * 8 < il) {
                    #pragma unroll
                    for (int r = c * 8; r < CEND(c); ++r) vs[r & 3] += P[r];
                }
            }
            const float v = (vs[0] + vs[1]) + (vs[2] + vs[3]);
            const float cs = vcol ? cmarg * __builtin_amdgcn_rcpf(v) : 0.0f;
            if (it < 2) {
                #pragma unroll
                for (int c = 0; c < 5; ++c) {
                    if (c * 8 < il) {
                        #pragma unroll
                        for (int r = c * 8; r < CEND(c); ++r) P[r] *= cs;
                    }
                }
            } else {
                csave = cs;                               // fold last scale into dot
            }
        }

        float ls[4] = {0.f, 0.f, 0.f, 0.f};
        #pragma unroll
        for (int c = 0; c < 5; ++c) {
            if (c * 8 < il) {
                #pragma unroll
                for (int r = c * 8; r < CEND(c); ++r) {
                    const float f = FGR(r);
                    const float fm = (r < il) ? f : 0.0f;   // mask BEFORE multiply
                    ls[r & 3] = fmaf(fm, P[r], ls[r & 3]);
                }
            }
        }
        float local = csave * ((ls[0] + ls[1]) + (ls[2] + ls[3]));
        local = wave_sum_fast(local);
        if (lane == 0) out[i * 128 + t] = local;
        #undef FGR
        #undef CEND
    }
}

extern "C" void kernel_launch(void* const* d_in, const int* in_sizes, int n_in,
                              void* d_out, int out_size, void* d_ws, size_t ws_size,
                              hipStream_t stream) {
    const float* img_cls  = (const float*)d_in[0];
    const float* imgs     = (const float*)d_in[1];
    const float* cap_cls  = (const float*)d_in[2];
    const float* caps     = (const float*)d_in[3];
    const int*   img_lens = (const int*)d_in[4];
    const int*   cap_lens = (const int*)d_in[5];
    float* out = (float*)d_out;

    __half* Ah = (__half*)d_ws;                          // 64*80*1024 halves = 10.5 MB
    __half* Bh = Ah + (size_t)64 * 80 * 1024;            // 128*64*1024 halves = 16.8 MB

    norm_kernel<<<64 * 80 + 128 * 64, 256, 0, stream>>>(img_cls, imgs, cap_cls, caps, Ah, Bh);
    fused_kernel<<<4096, 256, 0, stream>>>(Ah, Bh, img_lens, cap_lens, out);
}

// Round 18
// 132.243 us; speedup vs baseline: 1.2352x; 1.0212x over previous
//
#include <hip/hip_runtime.h>
#include <hip/hip_fp16.h>

#define EPSF 1e-6f

typedef _Float16 f16x8 __attribute__((ext_vector_type(8)));
typedef float f32x4 __attribute__((ext_vector_type(4)));

#define BK 64                  // K-tile (halves); LDS A row = 128 B (8 x 16B segs)
#define SMEM_BYTES 40960       // 4 x 10240 A staging (4 fg regions x 9472 alias inside)
#define BUF_BYTES 10240        // A staging: 80 rows x 128 B

#define AS1 __attribute__((address_space(1)))
#define AS3 __attribute__((address_space(3)))

#define VM_WAIT(N) asm volatile("s_waitcnt vmcnt(" #N ")" ::: "memory")
#define LGKM0()    asm volatile("s_waitcnt lgkmcnt(0)" ::: "memory")

// ---------- wave sum -> scalar (SGPR), fused-DPP version ----------
__device__ __forceinline__ float wave_sum_fast(float x) {
    asm volatile(
        "s_nop 1\n\t"
        "v_add_f32 %0, %0, %0 quad_perm:[1,0,3,2] row_mask:0xf bank_mask:0xf bound_ctrl:0\n\t"
        "s_nop 1\n\t"
        "v_add_f32 %0, %0, %0 quad_perm:[2,3,0,1] row_mask:0xf bank_mask:0xf bound_ctrl:0\n\t"
        "s_nop 1\n\t"
        "v_add_f32 %0, %0, %0 row_half_mirror row_mask:0xf bank_mask:0xf bound_ctrl:0\n\t"
        "s_nop 1\n\t"
        "v_add_f32 %0, %0, %0 row_mirror row_mask:0xf bank_mask:0xf bound_ctrl:0\n\t"
        "s_nop 1\n\t"
        "v_add_f32 %0, %0, %0 row_bcast:15 row_mask:0xf bank_mask:0xf bound_ctrl:0\n\t"
        "s_nop 1\n\t"
        "v_add_f32 %0, %0, %0 row_bcast:31 row_mask:0xf bank_mask:0xf bound_ctrl:0"
        : "+v"(x));
    return __int_as_float(__builtin_amdgcn_readlane(__float_as_int(x), 63));
}

// TWO chains interleaved in ONE asm block: chain B's stage-k add fills
// chain A's 2 DPP wait-states exactly -> zero s_nops, 2 sums in the issue
// time one serial chain used to take.
__device__ __forceinline__ void wave_sum2(float& x0, float& x1) {
    asm volatile(
        "s_nop 1\n\t"
        "v_add_f32 %0, %0, %0 quad_perm:[1,0,3,2] row_mask:0xf bank_mask:0xf bound_ctrl:0\n\t"
        "v_add_f32 %1, %1, %1 quad_perm:[1,0,3,2] row_mask:0xf bank_mask:0xf bound_ctrl:0\n\t"
        "v_add_f32 %0, %0, %0 quad_perm:[2,3,0,1] row_mask:0xf bank_mask:0xf bound_ctrl:0\n\t"
        "v_add_f32 %1, %1, %1 quad_perm:[2,3,0,1] row_mask:0xf bank_mask:0xf bound_ctrl:0\n\t"
        "v_add_f32 %0, %0, %0 row_half_mirror row_mask:0xf bank_mask:0xf bound_ctrl:0\n\t"
        "v_add_f32 %1, %1, %1 row_half_mirror row_mask:0xf bank_mask:0xf bound_ctrl:0\n\t"
        "v_add_f32 %0, %0, %0 row_mirror row_mask:0xf bank_mask:0xf bound_ctrl:0\n\t"
        "v_add_f32 %1, %1, %1 row_mirror row_mask:0xf bank_mask:0xf bound_ctrl:0\n\t"
        "v_add_f32 %0, %0, %0 row_bcast:15 row_mask:0xf bank_mask:0xf bound_ctrl:0\n\t"
        "v_add_f32 %1, %1, %1 row_bcast:15 row_mask:0xf bank_mask:0xf bound_ctrl:0\n\t"
        "v_add_f32 %0, %0, %0 row_bcast:31 row_mask:0xf bank_mask:0xf bound_ctrl:0\n\t"
        "v_add_f32 %1, %1, %1 row_bcast:31 row_mask:0xf bank_mask:0xf bound_ctrl:0"
        : "+v"(x0), "+v"(x1));
    x0 = __int_as_float(__builtin_amdgcn_readlane(__float_as_int(x0), 63));
    x1 = __int_as_float(__builtin_amdgcn_readlane(__float_as_int(x1), 63));
}

// ---------------- Phase 1: prepend cls, +EPS, L2-normalize, store fp16 ----------------
// A: row-major [64 groups][80 rows][1024]; rows 0..36 = img 2g, 37..73 = img 2g+1.
// B: FRAGMENT-MAJOR by K-32 subtile: Bh[((t*32 + k32)*4 + n)*512 + lane*8].
__global__ __launch_bounds__(256) void norm_kernel(
        const float* __restrict__ img_cls, const float* __restrict__ imgs,
        const float* __restrict__ cap_cls, const float* __restrict__ caps,
        __half* __restrict__ Ah, __half* __restrict__ Bh) {
    __shared__ float red[4];
    const int row = blockIdx.x;
    const int tid = threadIdx.x;

    const float* src = nullptr;
    __half* dsth;
    float eps_add = EPSF;
    if (row < 64 * 80) {
        const int g = row / 80, r = row % 80;
        dsth = Ah + (size_t)row * 1024 + tid * 4;
        int i = -1, rr = 0;
        if (r < 37)      { i = 2 * g;     rr = r; }
        else if (r < 74) { i = 2 * g + 1; rr = r - 37; }
        if (i >= 0) {
            if (rr == 0) { src = img_cls + (size_t)i * 1024; eps_add = 0.0f; }
            else         { src = imgs + ((size_t)i * 36 + (rr - 1)) * 1024; }
        }
    } else {
        const int row2 = row - 64 * 80;
        const int t = row2 >> 6, r = row2 & 63;
        const int n = r >> 4, fr = r & 15;
        const int kt = tid >> 3, q4 = (tid >> 1) & 3, j = (tid & 1) * 4;
        dsth = Bh + ((size_t)(t * 32 + kt) * 4 + n) * 512 + (q4 * 16 + fr) * 8 + j;
        if (r == 0)       { src = cap_cls + (size_t)t * 1024; eps_add = 0.0f; }
        else if (r <= 50) { src = caps + ((size_t)t * 50 + (r - 1)) * 1024; }
    }

    if (src == nullptr) {  // pad row: zeros (uniform across block)
        ushort4 z; z.x = z.y = z.z = z.w = 0;
        *reinterpret_cast<ushort4*>(dsth) = z;
        return;
    }

    float4 v = reinterpret_cast<const float4*>(src)[tid];
    v.x += eps_add; v.y += eps_add; v.z += eps_add; v.w += eps_add;
    float ss = v.x * v.x + v.y * v.y + v.z * v.z + v.w * v.w;
    #pragma unroll
    for (int m = 1; m <= 32; m <<= 1) ss += __shfl_xor(ss, m);
    if ((tid & 63) == 0) red[tid >> 6] = ss;
    __syncthreads();
    const float tot = red[0] + red[1] + red[2] + red[3];
    const float rn = 1.0f / sqrtf(tot);

    ushort4 o;
    o.x = __half_as_ushort(__float2half(v.x * rn));
    o.y = __half_as_ushort(__float2half(v.y * rn));
    o.z = __half_as_ushort(__float2half(v.z * rn));
    o.w = __half_as_ushort(__float2half(v.w * rn));
    *reinterpret_cast<ushort4*>(dsth) = o;
}

// ---------------- Phase 2: fused GEMM (BK=64, 16 tiles, 8 supersteps) + Sinkhorn ----------------
// Block tile 80 A rows x 128 B cols, 256 threads / 4 waves; acc 5x2 = 40 AGPR.
// 4 blocks/CU.  A in LDS: FOUR 10,240-B buffers in two pairs; superstep s
// (tiles 2s, 2s+1) reads pair (s&1), stages tiles 2s+2, 2s+3 into the other
// pair.  ONE barrier per superstep (8 total).  B: THREE 2-frag register
// buffers (24 VGPR), consume-then-overwrite rotation (period 3).
// 10 A-octets/tile: wave w takes o=w, w+4 (+ w+8 if w<2) -> a = 3 / 2.
// vmcnt: mid leaves 2+2a (8/6); end leaves 2.
__device__ __forceinline__ void stage_octA(const __half* __restrict__ Ag,
                                           __half* buf, int kb, int o, size_t lofs) {
    const __half* src = Ag + (size_t)o * 8192 + kb + lofs;   // 8 rows x 1024 halves
    __builtin_amdgcn_global_load_lds((const AS1 void*)src,
                                     (AS3 void*)(buf + o * 512), 16, 0, 0);
}

__device__ __forceinline__ void stage_A(const __half* __restrict__ Ag,
                                        __half* buf, int kb, int wave, size_t lofs) {
    stage_octA(Ag, buf, kb, wave, lofs);
    stage_octA(Ag, buf, kb, wave + 4, lofs);
    if (wave < 2) stage_octA(Ag, buf, kb, wave + 8, lofs);
}

template <int KS>
__device__ __forceinline__ void ds_af(const __half* buf, int fr, int q4,
                                      f16x8 af[5]) {
    const int soff = (((KS * 4 + q4) ^ (fr & 7)) * 8);   // swizzled seg, halves
    #pragma unroll
    for (int m = 0; m < 5; ++m) {
        const int R = m * 16 + fr;
        af[m] = *reinterpret_cast<const f16x8*>(buf + R * BK + soff);
    }
}

// load one K-32 subtile (2 frags) of this wave's B columns
__device__ __forceinline__ void load_bf2(const __half* __restrict__ Bgw, int k32,
                                         f16x8 bf[2]) {
    const __half* p = Bgw + (size_t)k32 * 2048;   // Bgw has +frag_base+lane*8
    bf[0] = *reinterpret_cast<const f16x8*>(p);
    bf[1] = *reinterpret_cast<const f16x8*>(p + 512);
}

__device__ __forceinline__ void mfma_cluster(f32x4 acc[5][2], const f16x8 af[5],
                                             const f16x8 bf[2]) {
    __builtin_amdgcn_s_setprio(1);
    #pragma unroll
    for (int m = 0; m < 5; ++m)
        #pragma unroll
        for (int n = 0; n < 2; ++n)
            acc[m][n] = __builtin_amdgcn_mfma_f32_16x16x32_f16(af[m], bf[n], acc[m][n], 0, 0, 0);
    __builtin_amdgcn_s_setprio(0);
}

__global__ __launch_bounds__(256, 4) void fused_kernel(
        const __half* __restrict__ Ah, const __half* __restrict__ Bh,
        const int* __restrict__ img_lens, const int* __restrict__ cap_lens,
        float* __restrict__ out) {
    __shared__ __align__(16) char smem[SMEM_BYTES];   // 40,960 B x 4 blocks = 160 KiB
    __half* lds0 = reinterpret_cast<__half*>(smem);
    __half* lds1 = reinterpret_cast<__half*>(smem + BUF_BYTES);
    __half* lds2 = reinterpret_cast<__half*>(smem + 2 * BUF_BYTES);
    __half* lds3 = reinterpret_cast<__half*>(smem + 3 * BUF_BYTES);

    // XCD-chunked mapping: 8 consecutive blocks share bx across 8 by slices.
    const int idx = blockIdx.x;            // 0..4095
    const int xcd = idx & 7;
    const int within = idx >> 3;           // 0..511
    const int bx = within >> 3;            // 0..63  (A group = img pair)
    const int by = xcd * 8 + (within & 7); // 0..63  (cap pair)

    const int tid = threadIdx.x;
    const int wave = tid >> 6;             // 0..3
    const int lane = tid & 63;
    const int fr = lane & 15;
    const int q4 = lane >> 4;

    const __half* Ag = Ah + (size_t)bx * 80 * 1024;
    // wave's cap t = 2by + (wave>>1); frag base = (wave&1)*2 frags
    const __half* Bgw = Bh + (size_t)(2 * by + (wave >> 1)) * 65536
                           + (size_t)((wave & 1) * 2) * 512 + lane * 8;

    // A staging source: rsub = lane>>3 (row in 8-row octet); stored slot
    // (lane&7) holds global seg (lane&7) ^ rsub.  LDS dest linear.
    const int rsub8 = lane >> 3;
    const int segsrc = (lane & 7) ^ rsub8;
    const size_t lofs = (size_t)rsub8 * 1024 + (size_t)(segsrc * 8);

    f32x4 acc[5][2];
    #pragma unroll
    for (int m = 0; m < 5; ++m)
        #pragma unroll
        for (int n = 0; n < 2; ++n) {
            f32x4 z = {0.0f, 0.0f, 0.0f, 0.0f};
            acc[m][n] = z;
        }

    f16x8 b0[2], b1[2], b2[2];

    // Prologue.  Queue: [B(0,ks0)·2, B(0,ks1)·2, A0·a, A1·a, B(1,ks0)·2,
    // A2·a, A3·a]; wait leaves 2+2a -> B(0,*), A0, A1 landed.
    load_bf2(Bgw, 0, b0);
    load_bf2(Bgw, 1, b1);
    stage_A(Ag, lds0, 0, wave, lofs);
    stage_A(Ag, lds1, BK, wave, lofs);
    load_bf2(Bgw, 2, b2);
    stage_A(Ag, lds2, 2 * BK, wave, lofs);
    stage_A(Ag, lds3, 3 * BK, wave, lofs);
    if (wave < 2) { VM_WAIT(8); } else { VM_WAIT(6); }
    __builtin_amdgcn_s_barrier();

    // ---- superstep 0 (tiles 0,1; reads L0,L1; no staging) ----
    {
        f16x8 af[5];
        ds_af<0>(lds0, fr, q4, af);
        mfma_cluster(acc, af, b0);             // B(0,ks0)
        load_bf2(Bgw, 3, b0);                  // B(1,ks1)
        ds_af<1>(lds0, fr, q4, af);
        mfma_cluster(acc, af, b1);             // B(0,ks1)
        load_bf2(Bgw, 4, b1);                  // B(2,ks0)
        VM_WAIT(2);                            // k32 2,3 + A2,A3 landed
        ds_af<0>(lds1, fr, q4, af);
        mfma_cluster(acc, af, b2);             // B(1,ks0)
        load_bf2(Bgw, 5, b2);                  // B(2,ks1)
        ds_af<1>(lds1, fr, q4, af);
        mfma_cluster(acc, af, b0);             // B(1,ks1)
        load_bf2(Bgw, 6, b0);                  // B(3,ks0)
        LGKM0();
        VM_WAIT(2);                            // k32 4,5 landed; k32 6 in flight
        __builtin_amdgcn_s_barrier();
    }

    // ---- supersteps 1..6 (tiles 2..13): read pair s&1, stage other pair ----
    #define SSTEP(T, R0, R1, S0, S1, X, Y, Z)                         \
    {                                                                 \
        f16x8 af[5];                                                  \
        ds_af<0>((R0), fr, q4, af);                                   \
        mfma_cluster(acc, af, (X));                                   \
        load_bf2(Bgw, 2 * (T) + 3, (X));                              \
        ds_af<1>((R0), fr, q4, af);                                   \
        mfma_cluster(acc, af, (Y));                                   \
        load_bf2(Bgw, 2 * (T) + 4, (Y));                              \
        stage_A(Ag, (S0), ((T) + 2) * BK, wave, lofs);                \
        stage_A(Ag, (S1), ((T) + 3) * BK, wave, lofs);                \
        if (wave < 2) { VM_WAIT(8); } else { VM_WAIT(6); }            \
        ds_af<0>((R1), fr, q4, af);                                   \
        mfma_cluster(acc, af, (Z));                                   \
        load_bf2(Bgw, 2 * (T) + 5, (Z));                              \
        ds_af<1>((R1), fr, q4, af);                                   \
        mfma_cluster(acc, af, (X));                                   \
        load_bf2(Bgw, 2 * (T) + 6, (X));                              \
        LGKM0();                                                      \
        VM_WAIT(2);                                                   \
        __builtin_amdgcn_s_barrier();                                 \
    }

    SSTEP(2,  lds2, lds3, lds0, lds1, b1, b2, b0);   // s=1
    SSTEP(4,  lds0, lds1, lds2, lds3, b2, b0, b1);   // s=2
    SSTEP(6,  lds2, lds3, lds0, lds1, b0, b1, b2);   // s=3
    SSTEP(8,  lds0, lds1, lds2, lds3, b1, b2, b0);   // s=4
    SSTEP(10, lds2, lds3, lds0, lds1, b2, b0, b1);   // s=5
    SSTEP(12, lds0, lds1, lds2, lds3, b0, b1, b2);   // s=6: stages A14,A15 -> L2,L3
    #undef SSTEP

    // ---- superstep 7 (tiles 14,15; reads L2,L3; no staging/barrier) ----
    {
        f16x8 af[5];
        ds_af<0>(lds2, fr, q4, af);
        mfma_cluster(acc, af, b1);             // B(14,ks0) = k32 28
        load_bf2(Bgw, 31, b1);                 // B(15,ks1)
        ds_af<1>(lds2, fr, q4, af);
        mfma_cluster(acc, af, b2);             // B(14,ks1) = k32 29
        VM_WAIT(0);                            // k32 30, 31 landed
        ds_af<0>(lds3, fr, q4, af);
        mfma_cluster(acc, af, b0);             // B(15,ks0) = k32 30
        ds_af<1>(lds3, fr, q4, af);
        mfma_cluster(acc, af, b1);             // B(15,ks1) = k32 31
    }

    __syncthreads();   // staging buffers become fg scratch (block-shared)

    // ---------------- fg scatter: 4 regions of 37x64 f32 (9,472 B each) ----------------
    // Region rg = s*2 + tt covers (img 2bx+s, cap 2by+tt).  Wave w (cap
    // tt = w>>1, col half = w&1) writes rows 0..73 x its 32 cols.
    // Cols XOR-swizzled: col ^ (((sr>>2)&3)<<4) -> Sinkhorn reads conflict-free.
    float* fgall = reinterpret_cast<float*>(smem);
    {
        const int ttw = wave >> 1;
        #pragma unroll
        for (int m = 0; m < 5; ++m) {
            #pragma unroll
            for (int q = 0; q < 4; ++q) {
                const int Rl = m * 16 + q4 * 4 + q;     // 0..79
                const int s = (Rl >= 37) ? 1 : 0;
                const int sr = Rl - 37 * s;             // scratch row
                const bool valid = (Rl < 74);
                const int rg = s * 2 + ttw;
                const int sw = ((sr >> 2) & 3) << 4;
                #pragma unroll
                for (int n = 0; n < 2; ++n) {
                    const int sc = (wave & 1) * 32 + n * 16 + fr;
                    if (valid)
                        fgall[rg * 2368 + sr * 64 + (sc ^ sw)] = acc[m][n][q];
                }
            }
        }
    }
    __syncthreads();   // all 4 regions complete

    // ---------------- Sinkhorn: chunk-skipped, paired DPP, DEFERRED-SCALE ----------------
    // Wave w handles region w: img i = 2bx + (w>>1), cap t = 2by + (w&1).
    // Uniform scales (global s0, per-iter col scale csu) are NOT applied to
    // P in their own 37-wide loops; a pending scalar `spend` folds into the
    // next row-rescale: u_log = fma(spend, u_reg, EPS), P *= (spend*rmarg)
    // * rcp(u_log).  Valid because invalid-lane P == 0, making the col
    // scale effectively uniform.  Deletes 3 x 37-wide multiply loops.
    {
        float* fg = fgall + wave * 2368;
        const int i = 2 * bx + (wave >> 1);
        const int t = 2 * by + (wave & 1);
        const int il = img_lens[i] + 1;        // 2..37
        const int cl = cap_lens[t] + 1;        // 2..51
        const bool vcol = lane < cl;

        #define FGR(r_) fg[(r_) * 64 + (lane ^ ((((r_) >> 2) & 3) << 4))]
        #define CEND(c_) ((((c_) * 8 + 8) < 37) ? ((c_) * 8 + 8) : 37)

        float P[37];
        #pragma unroll
        for (int r = 0; r < 37; ++r) P[r] = 0.0f;

        float ts[4] = {0.f, 0.f, 0.f, 0.f};
        #pragma unroll
        for (int c = 0; c < 5; ++c) {
            if (c * 8 < il) {                       // wave-uniform chunk skip
                #pragma unroll
                for (int r = c * 8; r < CEND(c); ++r) {
                    const float f = FGR(r);
                    const bool act = (r < il) && vcol;
                    const float pe = act ? __expf((f - 1.0f) * 10.0f) : 0.0f;
                    P[r] = pe;
                    ts[r & 3] += pe;
                }
            }
        }
        float tot = (ts[0] + ts[1]) + (ts[2] + ts[3]);
        tot = wave_sum_fast(tot);

        const float rmarg = 1.0f / (float)il;
        const float cmarg = 1.0f / (float)cl;
        float spend = __builtin_amdgcn_rcpf(tot + EPSF);  // pending uniform scale
        float csave = 0.0f;
        for (int it = 0; it < 3; ++it) {
            const float srf = spend * rmarg;
            #pragma unroll
            for (int c = 0; c < 5; ++c) {
                if (c * 8 < il) {                   // wave-uniform chunk skip
                    #pragma unroll
                    for (int r = c * 8; r < CEND(c); r += 2) {
                        if (r + 1 < CEND(c)) {      // paired: interleaved chains
                            float u0 = P[r], u1 = P[r + 1];
                            wave_sum2(u0, u1);
                            P[r]     *= srf * __builtin_amdgcn_rcpf(fmaf(spend, u0, EPSF));
                            P[r + 1] *= srf * __builtin_amdgcn_rcpf(fmaf(spend, u1, EPSF));
                        } else {                    // odd tail row (r = 36)
                            const float u = wave_sum_fast(P[r]);
                            P[r] *= srf * __builtin_amdgcn_rcpf(fmaf(spend, u, EPSF));
                        }
                    }
                }
            }
            float vs[4] = {EPSF, 0.f, 0.f, 0.f};
            #pragma unroll
            for (int c = 0; c < 5; ++c) {
                if (c * 8 < il) {
                    #pragma unroll
                    for (int r = c * 8; r < CEND(c); ++r) vs[r & 3] += P[r];
                }
            }
            const float v = (vs[0] + vs[1]) + (vs[2] + vs[3]);
            const float csu = cmarg * __builtin_amdgcn_rcpf(v);   // uniform: P invalid = 0
            if (it < 2) spend = csu;               // defer to next row pass
            else        csave = csu;               // fold into dot
        }

        float ls[4] = {0.f, 0.f, 0.f, 0.f};
        #pragma unroll
        for (int c = 0; c < 5; ++c) {
            if (c * 8 < il) {
                #pragma unroll
                for (int r = c * 8; r < CEND(c); ++r) {
                    const float f = FGR(r);
                    const float fm = (r < il) ? f : 0.0f;   // mask BEFORE multiply
                    ls[r & 3] = fmaf(fm, P[r], ls[r & 3]);
                }
            }
        }
        float local = csave * ((ls[0] + ls[1]) + (ls[2] + ls[3]));
        local = wave_sum_fast(local);
        if (lane == 0) out[i * 128 + t] = local;
        #undef FGR
        #undef CEND
    }
}

extern "C" void kernel_launch(void* const* d_in, const int* in_sizes, int n_in,
                              void* d_out, int out_size, void* d_ws, size_t ws_size,
                              hipStream_t stream) {
    const float* img_cls  = (const float*)d_in[0];
    const float* imgs     = (const float*)d_in[1];
    const float* cap_cls  = (const float*)d_in[2];
    const float* caps     = (const float*)d_in[3];
    const int*   img_lens = (const int*)d_in[4];
    const int*   cap_lens = (const int*)d_in[5];
    float* out = (float*)d_out;

    __half* Ah = (__half*)d_ws;                          // 64*80*1024 halves = 10.5 MB
    __half* Bh = Ah + (size_t)64 * 80 * 1024;            // 128*64*1024 halves = 16.8 MB

    norm_kernel<<<64 * 80 + 128 * 64, 256, 0, stream>>>(img_cls, imgs, cap_cls, caps, Ah, Bh);
    fused_kernel<<<4096, 256, 0, stream>>>(Ah, Bh, img_lens, cap_lens, out);
}